// Round 17
// baseline (235.229 us; speedup 1.0000x reference)
//
#include <hip/hip_runtime.h>
#include <hip/hip_bf16.h>

typedef unsigned short u16;
typedef unsigned int u32;
typedef __attribute__((ext_vector_type(8))) unsigned short u16x8;
typedef __attribute__((ext_vector_type(8))) short s16x8;
typedef __attribute__((ext_vector_type(4))) float f32x4;
typedef __attribute__((ext_vector_type(16))) float f32x16;

#define NB 2
#define NLQ 2048
#define NLKV 4096
#define ND 1024
#define NH 16
#define NHD 64
#define SCALE 0.125f
#define QSC (SCALE * 1.44269504f)  // fold scale+log2e into Q

// async global->LDS, 16B per lane; dest = uniform base + lane*16
#define GL16(g, l)                                                            \
    __builtin_amdgcn_global_load_lds(                                         \
        (const __attribute__((address_space(1))) void*)(g),                   \
        (__attribute__((address_space(3))) void*)(l), 16, 0, 0)

__device__ __forceinline__ u16 f2bf(float f) {
    __hip_bfloat16 h = __float2bfloat16(f);
    return *(u16*)&h;
}

__device__ __forceinline__ float fast_exp2(float x) {
    float r;
    asm("v_exp_f32 %0, %1" : "=v"(r) : "v"(x));
    return r;
}

__device__ __forceinline__ u32 pkbf(float lo, float hi_) {
    u32 r;
    asm("v_cvt_pk_bf16_f32 %0, %1, %2" : "=v"(r) : "v"(lo), "v"(hi_));
    return r;
}

// vdst.hi32lanes <-> vsrc.lo32lanes
__device__ __forceinline__ void pl32swap(u32& a, u32& b) {
    asm("v_permlane32_swap_b32 %0, %1" : "+v"(a), "+v"(b));
}

// ---------- fused f32->bf16 (x_q, x_kv) + mask->bf16 in one launch ----------
__global__ __launch_bounds__(256) void cvt2_kernel(const float* __restrict__ xq,
                                                   const float* __restrict__ xkv,
                                                   const int* __restrict__ mask,
                                                   u16* __restrict__ oq,
                                                   u16* __restrict__ okv,
                                                   u16* __restrict__ mbf) {
    int bid = blockIdx.x;
    if (bid >= 6144) {  // mask blocks: 32 blocks x 256 = 8192 ints
        int g = (bid - 6144) * 256 + threadIdx.x;
        mbf[g] = mask[g] ? 0x3F80 : 0;  // bf16 1.0
        return;
    }
    const float* in;
    u16* out;
    int i0;
    if (bid < 2048) { in = xq; out = oq; i0 = bid; }
    else { in = xkv; out = okv; i0 = bid - 2048; }
    int i = i0 * 256 + threadIdx.x;
    const float4* p = (const float4*)in;
    float4 a = p[2 * i], b = p[2 * i + 1];
    u16x8 o;
    o[0] = f2bf(a.x); o[1] = f2bf(a.y); o[2] = f2bf(a.z); o[3] = f2bf(a.w);
    o[4] = f2bf(b.x); o[5] = f2bf(b.y); o[6] = f2bf(b.z); o[7] = f2bf(b.w);
    ((u16x8*)out)[i] = o;
}

// ---------- W[k][n] f32 -> Wt[n][k] bf16, 4 weights ----------
__global__ __launch_bounds__(256) void tcvt_kernel(
    const float* __restrict__ w0, const float* __restrict__ w1,
    const float* __restrict__ w2, const float* __restrict__ w3,
    u16* __restrict__ o0, u16* __restrict__ o1,
    u16* __restrict__ o2, u16* __restrict__ o3) {
    const float* w = blockIdx.z == 0 ? w0 : blockIdx.z == 1 ? w1 : blockIdx.z == 2 ? w2 : w3;
    u16* o = blockIdx.z == 0 ? o0 : blockIdx.z == 1 ? o1 : blockIdx.z == 2 ? o2 : o3;
    __shared__ float t[32][33];
    int n0 = blockIdx.x * 32, k0 = blockIdx.y * 32;
    int tx = threadIdx.x, ty = threadIdx.y;
#pragma unroll
    for (int i = 0; i < 4; i++) t[ty + 8 * i][tx] = w[(k0 + ty + 8 * i) * ND + n0 + tx];
    __syncthreads();
#pragma unroll
    for (int i = 0; i < 4; i++) o[(n0 + ty + 8 * i) * ND + k0 + tx] = f2bf(t[tx][ty + 8 * i]);
}

// ---------- unified QKV projection GEMM, m97-exact config ----------
// 1280 blocks (256 Q + 1024 KV), XCD-bijective swizzle. 256 thr = 4 waves 2x2,
// tile 128x128, BK=32, acc[4][4] (16 MFMA per 8 ds_read_b128 — the measured
// 874-912 TF structure). GL16 staging, 2 chunks/thread/matrix.
// V-half blocks swap MFMA operands -> D^T in acc -> coalesced V^T store.
__global__ __launch_bounds__(256) void qkv_kernel(
    const u16* __restrict__ xq, const u16* __restrict__ xkv,
    const u16* __restrict__ wq_t, const u16* __restrict__ wkv_t,
    const float* __restrict__ bq, const float* __restrict__ bk,
    const float* __restrict__ bv, const int* __restrict__ vmask,
    u16* __restrict__ Qh, u16* __restrict__ Kh, u16* __restrict__ VTh) {
    const int bid = blockIdx.x;
    const int swz = (bid & 7) * 160 + (bid >> 3);
    const bool isQ = swz < 256;
    int m0, n0;
    const u16 *A, *Bt;
    if (isQ) {
        m0 = (swz >> 3) * 128; n0 = (swz & 7) * 128;
        A = xq; Bt = wq_t;
    } else {
        int t2 = swz - 256;
        m0 = (t2 >> 4) * 128; n0 = (t2 & 15) * 128;
        A = xkv; Bt = wkv_t;
    }
    const bool isV = !isQ && n0 >= 1024;

    __shared__ __align__(16) u16 As[128 * 32];
    __shared__ __align__(16) u16 Bs[128 * 32];
    const int tid = threadIdx.x;
    const int lane = tid & 63, w = tid >> 6;
    const int wr = w >> 1, wc = w & 1;  // 2x2 wave grid; wave tile 64x64
    const int lr = lane & 15, lg = lane >> 4;
    const int ko = lg * 8;

    f32x4 acc[4][4];
#pragma unroll
    for (int i = 0; i < 4; i++)
#pragma unroll
        for (int j = 0; j < 4; j++)
#pragma unroll
            for (int r = 0; r < 4; r++) acc[i][j][r] = 0.f;

    // staging: 512 chunks of 16B per matrix; thread covers chunks tid and 256+tid
    const int srow = tid >> 2, spart = tid & 3;
    const u16* Ag1 = A + (size_t)(m0 + srow) * ND + spart * 8;
    const u16* Ag2 = A + (size_t)(m0 + 64 + srow) * ND + spart * 8;
    const u16* Bg1 = Bt + (size_t)(n0 + srow) * ND + spart * 8;
    const u16* Bg2 = Bt + (size_t)(n0 + 64 + srow) * ND + spart * 8;
    u16* lA1 = &As[w * 512];
    u16* lA2 = &As[2048 + w * 512];
    u16* lB1 = &Bs[w * 512];
    u16* lB2 = &Bs[2048 + w * 512];

    for (int kt = 0; kt < ND; kt += 32) {
        GL16(Ag1 + kt, lA1);
        GL16(Ag2 + kt, lA2);
        GL16(Bg1 + kt, lB1);
        GL16(Bg2 + kt, lB2);
        __syncthreads();

        s16x8 af[4], bf[4];
#pragma unroll
        for (int i = 0; i < 4; i++) {
            af[i] = *(const s16x8*)&As[(wr * 64 + i * 16 + lr) * 32 + ko];
            bf[i] = *(const s16x8*)&Bs[(wc * 64 + i * 16 + lr) * 32 + ko];
        }
        if (isV) {
#pragma unroll
            for (int mi = 0; mi < 4; mi++)
#pragma unroll
                for (int ni = 0; ni < 4; ni++)
                    acc[mi][ni] = __builtin_amdgcn_mfma_f32_16x16x32_bf16(
                        bf[ni], af[mi], acc[mi][ni], 0, 0, 0);
        } else {
#pragma unroll
            for (int mi = 0; mi < 4; mi++)
#pragma unroll
                for (int ni = 0; ni < 4; ni++)
                    acc[mi][ni] = __builtin_amdgcn_mfma_f32_16x16x32_bf16(
                        af[mi], bf[ni], acc[mi][ni], 0, 0, 0);
        }
        __syncthreads();
    }

#pragma unroll
    for (int mi = 0; mi < 4; mi++)
#pragma unroll
        for (int ni = 0; ni < 4; ni++)
#pragma unroll
            for (int r = 0; r < 4; r++) {
                if (isQ) {
                    int m = m0 + wr * 64 + mi * 16 + lg * 4 + r;
                    int n = n0 + wc * 64 + ni * 16 + lr;
                    int h = n >> 6, d = n & 63;
                    int b = m >> 11, lq = m & 2047;
                    Qh[((((size_t)b * NH + h) * NLQ + lq) << 6) + d] =
                        f2bf((acc[mi][ni][r] + bq[n]) * QSC);
                } else if (!isV) {
                    int m = m0 + wr * 64 + mi * 16 + lg * 4 + r;
                    int n = n0 + wc * 64 + ni * 16 + lr;
                    int h = n >> 6, d = n & 63;
                    int b = m >> 12, lkv = m & 4095;
                    Kh[((((size_t)b * NH + h) * NLKV + lkv) << 6) + d] =
                        f2bf(acc[mi][ni][r] + bk[n]);
                } else {
                    // transposed acc: row = n2 (d-dim), col = m (lkv, 16 consecutive)
                    int n2 = (n0 - 1024) + wc * 64 + ni * 16 + lg * 4 + r;
                    int m = m0 + wr * 64 + mi * 16 + lr;
                    int h = n2 >> 6, d = n2 & 63;
                    int b = m >> 12, lkv = m & 4095;
                    float val = vmask[(size_t)b * NLKV + lkv]
                                    ? acc[mi][ni][r] + bv[n2] : 0.f;
                    VTh[(((size_t)b * NH + h) * NHD + d) * NLKV + lkv] = f2bf(val);
                }
            }
}

// ---------- O-projection GEMM (f32 out), 64x128 tile -> 512 blocks (2/CU) ----------
// 256 thr = 4 waves 2x2; wave tile 32x64 (acc[2][4]). GL16 staging, BK=32.
__global__ __launch_bounds__(256) void ogemm_kernel(
    const u16* __restrict__ A, const u16* __restrict__ Bt,
    const float* __restrict__ bias, float* __restrict__ Cout) {
    __shared__ __align__(16) u16 As[64 * 32];
    __shared__ __align__(16) u16 Bs[128 * 32];
    const int m0 = blockIdx.x * 64;
    const int n0 = blockIdx.y * 128;
    const int tid = threadIdx.x;
    const int lane = tid & 63, w = tid >> 6;
    const int wr = w >> 1, wc = w & 1;  // 2x2 wave grid
    const int lr = lane & 15, lg = lane >> 4;
    const int ko = lg * 8;

    f32x4 acc[2][4];
#pragma unroll
    for (int i = 0; i < 2; i++)
#pragma unroll
        for (int j = 0; j < 4; j++)
#pragma unroll
            for (int r = 0; r < 4; r++) acc[i][j][r] = 0.f;

    const int srow = tid >> 2, spart = tid & 3;
    const u16* Ag = A + (size_t)(m0 + srow) * ND + spart * 8;
    const u16* Bg = Bt + (size_t)(n0 + srow) * ND + spart * 8;
    const u16* Bg2 = Bt + (size_t)(n0 + 64 + srow) * ND + spart * 8;
    u16* lA = &As[w * 512];
    u16* lB = &Bs[w * 512];
    u16* lB2 = &Bs[2048 + w * 512];

    for (int kt = 0; kt < ND; kt += 32) {
        GL16(Ag + kt, lA);
        GL16(Bg + kt, lB);
        GL16(Bg2 + kt, lB2);
        __syncthreads();

        s16x8 af[2], bf[4];
#pragma unroll
        for (int i = 0; i < 2; i++)
            af[i] = *(const s16x8*)&As[(wr * 32 + i * 16 + lr) * 32 + ko];
#pragma unroll
        for (int j = 0; j < 4; j++)
            bf[j] = *(const s16x8*)&Bs[(wc * 64 + j * 16 + lr) * 32 + ko];
#pragma unroll
        for (int mi = 0; mi < 2; mi++)
#pragma unroll
            for (int ni = 0; ni < 4; ni++)
                acc[mi][ni] = __builtin_amdgcn_mfma_f32_16x16x32_bf16(
                    af[mi], bf[ni], acc[mi][ni], 0, 0, 0);
        __syncthreads();
    }

#pragma unroll
    for (int mi = 0; mi < 2; mi++)
#pragma unroll
        for (int ni = 0; ni < 4; ni++)
#pragma unroll
            for (int r = 0; r < 4; r++) {
                int m = m0 + wr * 32 + mi * 16 + lg * 4 + r;
                int n = n0 + wc * 64 + ni * 16 + lr;
                Cout[(size_t)m * ND + n] = acc[mi][ni][r] + bias[n];
            }
}

// ---------- flash attention (R16-proven): swapped QK^T + setprio + swizzles ----------
__global__ __launch_bounds__(256) void attn_kernel(
    const u16* __restrict__ Qh, const u16* __restrict__ Kh,
    const u16* __restrict__ VTh, const u16* __restrict__ mbf,
    u16* __restrict__ attn) {
    const int l = blockIdx.x + 16 * blockIdx.y;
    const int qt = l >> 5;
    const int bh = (l & 7) * 4 + ((l >> 3) & 3);
    const int b = bh >> 4, h = bh & 15;
    const int tid = threadIdx.x;
    const int lane = tid & 63, w = tid >> 6;
    const int c = lane & 31, hi = lane >> 5;
    const int c7 = c & 7, c3 = (c >> 3) & 3;

    __shared__ __align__(16) u16 kt[2][4096];
    __shared__ __align__(16) u16 vt[2][4096];

    const int qw0 = qt * 128 + w * 32;
    const u16* Qb = Qh + (size_t)bh * NLQ * NHD;
    const u16* Kb = Kh + (size_t)bh * NLKV * NHD;
    const u16* VTb = VTh + (size_t)bh * NHD * NLKV;
    const u16* mbfb = mbf + (size_t)b * NLKV;

    // Q B-fragments: lane holds Q[qw0+c][kb*16 + hi*8 .. +7]
    s16x8 qa[4];
#pragma unroll
    for (int kb = 0; kb < 4; kb++)
        qa[kb] = *(const s16x8*)(Qb + (size_t)(qw0 + c) * NHD + kb * 16 + hi * 8);

    f32x16 o0, o1, lacc;
#pragma unroll
    for (int r = 0; r < 16; r++) { o0[r] = 0.f; o1[r] = 0.f; lacc[r] = 0.f; }

    // staging: row srow & srow+32, chunk sj; slot j holds logical chunk
    // j ^ (row&7) ^ ((row>>3)&3)   (key(row+32) == key(row))
    const int srow = 8 * w + (lane >> 3);
    const int sj = lane & 7;
    const int sx8 = (sj ^ (srow & 7) ^ ((srow >> 3) & 3)) * 8;
    const u16* kS1 = Kb + (size_t)srow * NHD + sx8;
    const u16* kS2 = Kb + (size_t)(srow + 32) * NHD + sx8;
    const u16* vS1 = VTb + (size_t)srow * NLKV + sx8;
    const u16* vS2 = VTb + (size_t)(srow + 32) * NLKV + sx8;
    const int d1 = w * 512, d2 = 2048 + w * 512;

    // prologue: stage tile 0 into buffer 0
    GL16(kS1, &kt[0][d1]);
    GL16(kS2, &kt[0][d2]);
    GL16(vS1, &vt[0][d1]);
    GL16(vS2, &vt[0][d2]);

    const int NT = NLKV / 64;
    for (int t = 0; t < NT; t++) {
        const int cur = t & 1;
        __syncthreads();  // buf[cur] staged (vmcnt drained) + buf[cur^1] free
        if (t + 1 < NT) {
            size_t kvo = (size_t)(t + 1) * 64;
            GL16(kS1 + kvo * NHD, &kt[cur ^ 1][d1]);
            GL16(kS2 + kvo * NHD, &kt[cur ^ 1][d2]);
            GL16(vS1 + kvo, &vt[cur ^ 1][d1]);
            GL16(vS2 + kvo, &vt[cur ^ 1][d2]);
        }
        // mask A-fragments (broadcast rows)
        s16x8 mf[4];
#pragma unroll
        for (int pb = 0; pb < 4; pb++)
            mf[pb] = *(const s16x8*)(mbfb + t * 64 + pb * 16 + hi * 8);

        const u16* ktc = kt[cur];
        const u16* vtc = vt[cur];

        // QK^T swapped: s0 = S^T rows kv 0..31, s1 = rows 32..63; col q = c
        f32x16 s0, s1;
#pragma unroll
        for (int r = 0; r < 16; r++) { s0[r] = 0.f; s1[r] = 0.f; }
        __builtin_amdgcn_s_setprio(1);
#pragma unroll
        for (int kb = 0; kb < 4; kb++) {
            int slot = ((kb * 2 + hi) ^ c7 ^ c3) << 3;
            s16x8 kf0 = *(const s16x8*)&ktc[c * 64 + slot];
            s16x8 kf1 = *(const s16x8*)&ktc[(32 + c) * 64 + slot];
            s0 = __builtin_amdgcn_mfma_f32_32x32x16_bf16(kf0, qa[kb], s0, 0, 0, 0);
            s1 = __builtin_amdgcn_mfma_f32_32x32x16_bf16(kf1, qa[kb], s1, 0, 0, 0);
        }
        __builtin_amdgcn_s_setprio(0);

        // softmax: pure exp2 (Q pre-scaled; mask via V-zeroing + l-MFMA)
        float p0a[16], p1a[16];
#pragma unroll
        for (int r = 0; r < 16; r++) {
            p0a[r] = fast_exp2(s0[r]);
            p1a[r] = fast_exp2(s1[r]);
        }

        // pack to bf16 pairs + permlane swap -> PV B-fragments
        u32 pka[8], pkb2[8];
#pragma unroll
        for (int i = 0; i < 8; i++) {
            pka[i] = pkbf(p0a[2 * i], p0a[2 * i + 1]);
            pkb2[i] = pkbf(p1a[2 * i], p1a[2 * i + 1]);
        }
        pl32swap(pka[0], pka[2]); pl32swap(pka[1], pka[3]);
        pl32swap(pka[4], pka[6]); pl32swap(pka[5], pka[7]);
        pl32swap(pkb2[0], pkb2[2]); pl32swap(pkb2[1], pkb2[3]);
        pl32swap(pkb2[4], pkb2[6]); pl32swap(pkb2[5], pkb2[7]);

        union { u32 u[4]; s16x8 h; } fr[4];
#pragma unroll
        for (int i = 0; i < 4; i++) {
            fr[0].u[i] = pka[i];
            fr[1].u[i] = pka[4 + i];
            fr[2].u[i] = pkb2[i];
            fr[3].u[i] = pkb2[4 + i];
        }

        // PV: O^T[d][q=c] += V^T[d][kv] * P ; l via mask-MFMA on same P frags
        __builtin_amdgcn_s_setprio(1);
#pragma unroll
        for (int pb = 0; pb < 4; pb++) {
            int slot = ((pb * 2 + hi) ^ c7 ^ c3) << 3;
            s16x8 vf0 = *(const s16x8*)&vtc[c * 64 + slot];
            s16x8 vf1 = *(const s16x8*)&vtc[(32 + c) * 64 + slot];
            o0 = __builtin_amdgcn_mfma_f32_32x32x16_bf16(vf0, fr[pb].h, o0, 0, 0, 0);
            o1 = __builtin_amdgcn_mfma_f32_32x32x16_bf16(vf1, fr[pb].h, o1, 0, 0, 0);
            lacc = __builtin_amdgcn_mfma_f32_32x32x16_bf16(mf[pb], fr[pb].h, lacc, 0, 0, 0);
        }
        __builtin_amdgcn_s_setprio(0);
    }

    // lacc rows are all identical = l[q=c] over the full kv range
    float linv = 1.f / lacc[0];

    // epilogue: transpose O through LDS (reuse kt), coalesced global write.
    __syncthreads();
    u32* osh = (u32*)kt + w * 1024;  // per-wave [32 rows][32 dwords]
#pragma unroll
    for (int r = 0; r < 16; r += 2) {
        int d = (r & 3) + 8 * (r >> 2) + 4 * hi;
        u32 plo = pkbf(o0[r] * linv, o0[r + 1] * linv);
        u32 phi = pkbf(o1[r] * linv, o1[r + 1] * linv);
        int dc0 = d >> 1, dc1 = (d + 32) >> 1;
        osh[c * 32 + (((dc0 >> 2) ^ c7) << 2) + (dc0 & 3)] = plo;
        osh[c * 32 + (((dc1 >> 2) ^ c7) << 2) + (dc1 & 3)] = phi;
    }
    __syncthreads();
#pragma unroll
    for (int i = 0; i < 4; i++) {
        int row = 8 * i + (lane >> 3);
        int jj = lane & 7;
        u32 v0 = osh[row * 32 + ((jj ^ (row & 7)) << 2) + 0];
        u32 v1 = osh[row * 32 + ((jj ^ (row & 7)) << 2) + 1];
        u32 v2 = osh[row * 32 + ((jj ^ (row & 7)) << 2) + 2];
        u32 v3 = osh[row * 32 + ((jj ^ (row & 7)) << 2) + 3];
        u32* gp = (u32*)(attn + ((size_t)b * NLQ + qw0 + row) * ND + h * NHD + jj * 8);
        gp[0] = v0; gp[1] = v1; gp[2] = v2; gp[3] = v3;
    }
}

extern "C" void kernel_launch(void* const* d_in, const int* in_sizes, int n_in,
                              void* d_out, int out_size, void* d_ws, size_t ws_size,
                              hipStream_t stream) {
    const float* x_q = (const float*)d_in[0];
    const float* x_kv = (const float*)d_in[1];
    const int* mask = (const int*)d_in[2];
    const float* Wq = (const float*)d_in[3];
    const float* bq = (const float*)d_in[4];
    const float* Wk = (const float*)d_in[5];
    const float* bk = (const float*)d_in[6];
    const float* Wv = (const float*)d_in[7];
    const float* bv = (const float*)d_in[8];
    const float* Wo = (const float*)d_in[9];
    const float* bo = (const float*)d_in[10];
    float* out = (float*)d_out;

    size_t off = 0;
    auto carve = [&](size_t bytes) {
        void* p = (char*)d_ws + off;
        off += (bytes + 255) & ~(size_t)255;
        return p;
    };
    u16* xq_bf = (u16*)carve((size_t)NB * NLQ * ND * 2);
    u16* xkv_bf = (u16*)carve((size_t)NB * NLKV * ND * 2);
    u16* wq_t = (u16*)carve((size_t)ND * ND * 2);
    u16* wkv_t = (u16*)carve((size_t)2 * ND * ND * 2);
    u16* wo_t = (u16*)carve((size_t)ND * ND * 2);
    u16* Qh = (u16*)carve((size_t)NB * NH * NLQ * NHD * 2);
    u16* Kh = (u16*)carve((size_t)NB * NH * NLKV * NHD * 2);
    u16* VTh = (u16*)carve((size_t)NB * NH * NLKV * NHD * 2);
    u16* attn_bf = (u16*)carve((size_t)NB * NLQ * ND * 2);
    u16* mbfw = (u16*)carve((size_t)NB * NLKV * 2);

    cvt2_kernel<<<dim3(6176), 256, 0, stream>>>(x_q, x_kv, mask, xq_bf, xkv_bf, mbfw);
    tcvt_kernel<<<dim3(32, 32, 4), dim3(32, 8), 0, stream>>>(
        Wq, Wk, Wv, Wo, wq_t, wkv_t, wkv_t + (size_t)ND * ND, wo_t);
    qkv_kernel<<<dim3(1280), 256, 0, stream>>>(xq_bf, xkv_bf, wq_t, wkv_t,
                                               bq, bk, bv, mask, Qh, Kh, VTh);
    attn_kernel<<<dim3(16, 32), 256, 0, stream>>>(Qh, Kh, VTh, mbfw, attn_bf);
    ogemm_kernel<<<dim3(64, 8), 256, 0, stream>>>(attn_bf, wo_t, bo, out);
}

// Round 18
// 215.013 us; speedup vs baseline: 1.0940x; 1.0940x over previous
//
#include <hip/hip_runtime.h>
#include <hip/hip_bf16.h>

typedef unsigned short u16;
typedef unsigned int u32;
typedef __attribute__((ext_vector_type(8))) unsigned short u16x8;
typedef __attribute__((ext_vector_type(8))) short s16x8;
typedef __attribute__((ext_vector_type(4))) float f32x4;
typedef __attribute__((ext_vector_type(16))) float f32x16;

#define NB 2
#define NLQ 2048
#define NLKV 4096
#define ND 1024
#define NH 16
#define NHD 64
#define SCALE 0.125f
#define QSC (SCALE * 1.44269504f)  // fold scale+log2e into Q

// async global->LDS, 16B per lane; dest = uniform base + lane*16
#define GL16(g, l)                                                            \
    __builtin_amdgcn_global_load_lds(                                         \
        (const __attribute__((address_space(1))) void*)(g),                   \
        (__attribute__((address_space(3))) void*)(l), 16, 0, 0)

__device__ __forceinline__ u16 f2bf(float f) {
    __hip_bfloat16 h = __float2bfloat16(f);
    return *(u16*)&h;
}

__device__ __forceinline__ float fast_exp2(float x) {
    float r;
    asm("v_exp_f32 %0, %1" : "=v"(r) : "v"(x));
    return r;
}

__device__ __forceinline__ u32 pkbf(float lo, float hi_) {
    u32 r;
    asm("v_cvt_pk_bf16_f32 %0, %1, %2" : "=v"(r) : "v"(lo), "v"(hi_));
    return r;
}

// vdst.hi32lanes <-> vsrc.lo32lanes
__device__ __forceinline__ void pl32swap(u32& a, u32& b) {
    asm("v_permlane32_swap_b32 %0, %1" : "+v"(a), "+v"(b));
}

// ---------- unified prep: x f32->bf16 | mask->bf16 | 4x weight transpose ----------
// blocks [0,6144): x convert; [6144,6176): mask; [6176,10272): tcvt (flat-indexed)
__global__ __launch_bounds__(256) void prep_kernel(
    const float* __restrict__ xq, const float* __restrict__ xkv,
    const int* __restrict__ mask,
    const float* __restrict__ w0, const float* __restrict__ w1,
    const float* __restrict__ w2, const float* __restrict__ w3,
    u16* __restrict__ oq, u16* __restrict__ okv, u16* __restrict__ mbf,
    u16* __restrict__ o0, u16* __restrict__ o1,
    u16* __restrict__ o2, u16* __restrict__ o3) {
    __shared__ float t[32][33];
    const int bid = blockIdx.x;
    const int tid = threadIdx.x;
    if (bid < 6144) {
        const float* in;
        u16* out;
        int i0;
        if (bid < 2048) { in = xq; out = oq; i0 = bid; }
        else { in = xkv; out = okv; i0 = bid - 2048; }
        int i = i0 * 256 + tid;
        const float4* p = (const float4*)in;
        float4 a = p[2 * i], b = p[2 * i + 1];
        u16x8 o;
        o[0] = f2bf(a.x); o[1] = f2bf(a.y); o[2] = f2bf(a.z); o[3] = f2bf(a.w);
        o[4] = f2bf(b.x); o[5] = f2bf(b.y); o[6] = f2bf(b.z); o[7] = f2bf(b.w);
        ((u16x8*)out)[i] = o;
        return;
    }
    if (bid < 6176) {
        int g = (bid - 6144) * 256 + tid;
        mbf[g] = mask[g] ? 0x3F80 : 0;  // bf16 1.0
        return;
    }
    // weight transpose: W[k][n] f32 -> Wt[n][k] bf16
    int tb = bid - 6176;
    int z = tb >> 10;
    int rem = tb & 1023;
    int n0 = (rem & 31) * 32, k0 = (rem >> 5) * 32;
    const float* w = z == 0 ? w0 : z == 1 ? w1 : z == 2 ? w2 : w3;
    u16* o = z == 0 ? o0 : z == 1 ? o1 : z == 2 ? o2 : o3;
    int tx = tid & 31, ty = tid >> 5;
#pragma unroll
    for (int i = 0; i < 4; i++) t[ty + 8 * i][tx] = w[(k0 + ty + 8 * i) * ND + n0 + tx];
    __syncthreads();
#pragma unroll
    for (int i = 0; i < 4; i++) o[(n0 + ty + 8 * i) * ND + k0 + tx] = f2bf(t[tx][ty + 8 * i]);
}

// ---------- unified QKV projection GEMM: 1280 blocks (256 Q + 1024 KV) ----------
// R16-proven config: XCD-bijective swizzle, tile 128x128, BK=32, 512 thr =
// 8 waves 2x4 (wave tile 64x32), GL16 staging. V-half blocks swap MFMA
// operands -> D^T in acc -> coalesced V^T store.
__global__ __launch_bounds__(512) void qkv_kernel(
    const u16* __restrict__ xq, const u16* __restrict__ xkv,
    const u16* __restrict__ wq_t, const u16* __restrict__ wkv_t,
    const float* __restrict__ bq, const float* __restrict__ bk,
    const float* __restrict__ bv, const int* __restrict__ vmask,
    u16* __restrict__ Qh, u16* __restrict__ Kh, u16* __restrict__ VTh) {
    const int bid = blockIdx.x;
    const int swz = (bid & 7) * 160 + (bid >> 3);
    const bool isQ = swz < 256;
    int m0, n0;
    const u16 *A, *Bt;
    if (isQ) {
        m0 = (swz >> 3) * 128; n0 = (swz & 7) * 128;
        A = xq; Bt = wq_t;
    } else {
        int t2 = swz - 256;
        m0 = (t2 >> 4) * 128; n0 = (t2 & 15) * 128;
        A = xkv; Bt = wkv_t;
    }
    const bool isV = !isQ && n0 >= 1024;

    __shared__ __align__(16) u16 As[128 * 32];
    __shared__ __align__(16) u16 Bs[128 * 32];
    const int tid = threadIdx.x;
    const int lane = tid & 63, w = tid >> 6;
    const int wr = w >> 2, wc = w & 3;
    const int lr = lane & 15, lg = lane >> 4;
    const int ko = lg * 8;

    f32x4 acc[4][2];
#pragma unroll
    for (int i = 0; i < 4; i++)
#pragma unroll
        for (int j = 0; j < 2; j++)
#pragma unroll
            for (int r = 0; r < 4; r++) acc[i][j][r] = 0.f;

    const int srow = tid >> 2, spart = tid & 3;
    const u16* Ag = A + (size_t)(m0 + srow) * ND + spart * 8;
    const u16* Bg = Bt + (size_t)(n0 + srow) * ND + spart * 8;
    u16* lA = &As[w * 512];
    u16* lB = &Bs[w * 512];

    for (int kt = 0; kt < ND; kt += 32) {
        GL16(Ag + kt, lA);
        GL16(Bg + kt, lB);
        __syncthreads();

        s16x8 af[4], bf[2];
#pragma unroll
        for (int i = 0; i < 4; i++)
            af[i] = *(const s16x8*)&As[(wr * 64 + i * 16 + lr) * 32 + ko];
#pragma unroll
        for (int j = 0; j < 2; j++)
            bf[j] = *(const s16x8*)&Bs[(wc * 32 + j * 16 + lr) * 32 + ko];
        if (isV) {
#pragma unroll
            for (int mi = 0; mi < 4; mi++)
#pragma unroll
                for (int ni = 0; ni < 2; ni++)
                    acc[mi][ni] = __builtin_amdgcn_mfma_f32_16x16x32_bf16(
                        bf[ni], af[mi], acc[mi][ni], 0, 0, 0);
        } else {
#pragma unroll
            for (int mi = 0; mi < 4; mi++)
#pragma unroll
                for (int ni = 0; ni < 2; ni++)
                    acc[mi][ni] = __builtin_amdgcn_mfma_f32_16x16x32_bf16(
                        af[mi], bf[ni], acc[mi][ni], 0, 0, 0);
        }
        __syncthreads();
    }

#pragma unroll
    for (int mi = 0; mi < 4; mi++)
#pragma unroll
        for (int ni = 0; ni < 2; ni++)
#pragma unroll
            for (int r = 0; r < 4; r++) {
                if (isQ) {
                    int m = m0 + wr * 64 + mi * 16 + lg * 4 + r;
                    int n = n0 + wc * 32 + ni * 16 + lr;
                    int h = n >> 6, d = n & 63;
                    int b = m >> 11, lq = m & 2047;
                    Qh[((((size_t)b * NH + h) * NLQ + lq) << 6) + d] =
                        f2bf((acc[mi][ni][r] + bq[n]) * QSC);
                } else if (!isV) {
                    int m = m0 + wr * 64 + mi * 16 + lg * 4 + r;
                    int n = n0 + wc * 32 + ni * 16 + lr;
                    int h = n >> 6, d = n & 63;
                    int b = m >> 12, lkv = m & 4095;
                    Kh[((((size_t)b * NH + h) * NLKV + lkv) << 6) + d] =
                        f2bf(acc[mi][ni][r] + bk[n]);
                } else {
                    // transposed acc: row = n2 (d-dim), col = m (lkv, 16 consecutive)
                    int n2 = (n0 - 1024) + wc * 32 + ni * 16 + lg * 4 + r;
                    int m = m0 + wr * 64 + mi * 16 + lr;
                    int h = n2 >> 6, d = n2 & 63;
                    int b = m >> 12, lkv = m & 4095;
                    float val = vmask[(size_t)b * NLKV + lkv]
                                    ? acc[mi][ni][r] + bv[n2] : 0.f;
                    VTh[(((size_t)b * NH + h) * NHD + d) * NLKV + lkv] = f2bf(val);
                }
            }
}

// ---------- O-projection GEMM (f32 out), 64x128 tile -> 512 blocks (2/CU) ----------
__global__ __launch_bounds__(256) void ogemm_kernel(
    const u16* __restrict__ A, const u16* __restrict__ Bt,
    const float* __restrict__ bias, float* __restrict__ Cout) {
    __shared__ __align__(16) u16 As[64 * 32];
    __shared__ __align__(16) u16 Bs[128 * 32];
    const int m0 = blockIdx.x * 64;
    const int n0 = blockIdx.y * 128;
    const int tid = threadIdx.x;
    const int lane = tid & 63, w = tid >> 6;
    const int wr = w >> 1, wc = w & 1;  // 2x2 wave grid
    const int lr = lane & 15, lg = lane >> 4;
    const int ko = lg * 8;

    f32x4 acc[2][4];
#pragma unroll
    for (int i = 0; i < 2; i++)
#pragma unroll
        for (int j = 0; j < 4; j++)
#pragma unroll
            for (int r = 0; r < 4; r++) acc[i][j][r] = 0.f;

    const int srow = tid >> 2, spart = tid & 3;
    const u16* Ag = A + (size_t)(m0 + srow) * ND + spart * 8;
    const u16* Bg = Bt + (size_t)(n0 + srow) * ND + spart * 8;
    const u16* Bg2 = Bt + (size_t)(n0 + 64 + srow) * ND + spart * 8;
    u16* lA = &As[w * 512];
    u16* lB = &Bs[w * 512];
    u16* lB2 = &Bs[2048 + w * 512];

    for (int kt = 0; kt < ND; kt += 32) {
        GL16(Ag + kt, lA);
        GL16(Bg + kt, lB);
        GL16(Bg2 + kt, lB2);
        __syncthreads();

        s16x8 af[2], bf[4];
#pragma unroll
        for (int i = 0; i < 2; i++)
            af[i] = *(const s16x8*)&As[(wr * 32 + i * 16 + lr) * 32 + ko];
#pragma unroll
        for (int j = 0; j < 4; j++)
            bf[j] = *(const s16x8*)&Bs[(wc * 64 + j * 16 + lr) * 32 + ko];
#pragma unroll
        for (int mi = 0; mi < 2; mi++)
#pragma unroll
            for (int ni = 0; ni < 4; ni++)
                acc[mi][ni] = __builtin_amdgcn_mfma_f32_16x16x32_bf16(
                    af[mi], bf[ni], acc[mi][ni], 0, 0, 0);
        __syncthreads();
    }

#pragma unroll
    for (int mi = 0; mi < 2; mi++)
#pragma unroll
        for (int ni = 0; ni < 4; ni++)
#pragma unroll
            for (int r = 0; r < 4; r++) {
                int m = m0 + wr * 32 + mi * 16 + lg * 4 + r;
                int n = n0 + wc * 64 + ni * 16 + lr;
                Cout[(size_t)m * ND + n] = acc[mi][ni][r] + bias[n];
            }
}

// ---------- flash attention (R16-proven): swapped QK^T + setprio + swizzles ----------
__global__ __launch_bounds__(256) void attn_kernel(
    const u16* __restrict__ Qh, const u16* __restrict__ Kh,
    const u16* __restrict__ VTh, const u16* __restrict__ mbf,
    u16* __restrict__ attn) {
    const int l = blockIdx.x + 16 * blockIdx.y;
    const int qt = l >> 5;
    const int bh = (l & 7) * 4 + ((l >> 3) & 3);
    const int b = bh >> 4, h = bh & 15;
    const int tid = threadIdx.x;
    const int lane = tid & 63, w = tid >> 6;
    const int c = lane & 31, hi = lane >> 5;
    const int c7 = c & 7, c3 = (c >> 3) & 3;

    __shared__ __align__(16) u16 kt[2][4096];
    __shared__ __align__(16) u16 vt[2][4096];

    const int qw0 = qt * 128 + w * 32;
    const u16* Qb = Qh + (size_t)bh * NLQ * NHD;
    const u16* Kb = Kh + (size_t)bh * NLKV * NHD;
    const u16* VTb = VTh + (size_t)bh * NHD * NLKV;
    const u16* mbfb = mbf + (size_t)b * NLKV;

    // Q B-fragments: lane holds Q[qw0+c][kb*16 + hi*8 .. +7]
    s16x8 qa[4];
#pragma unroll
    for (int kb = 0; kb < 4; kb++)
        qa[kb] = *(const s16x8*)(Qb + (size_t)(qw0 + c) * NHD + kb * 16 + hi * 8);

    f32x16 o0, o1, lacc;
#pragma unroll
    for (int r = 0; r < 16; r++) { o0[r] = 0.f; o1[r] = 0.f; lacc[r] = 0.f; }

    // staging: row srow & srow+32, chunk sj; slot j holds logical chunk
    // j ^ (row&7) ^ ((row>>3)&3)   (key(row+32) == key(row))
    const int srow = 8 * w + (lane >> 3);
    const int sj = lane & 7;
    const int sx8 = (sj ^ (srow & 7) ^ ((srow >> 3) & 3)) * 8;
    const u16* kS1 = Kb + (size_t)srow * NHD + sx8;
    const u16* kS2 = Kb + (size_t)(srow + 32) * NHD + sx8;
    const u16* vS1 = VTb + (size_t)srow * NLKV + sx8;
    const u16* vS2 = VTb + (size_t)(srow + 32) * NLKV + sx8;
    const int d1 = w * 512, d2 = 2048 + w * 512;

    // prologue: stage tile 0 into buffer 0
    GL16(kS1, &kt[0][d1]);
    GL16(kS2, &kt[0][d2]);
    GL16(vS1, &vt[0][d1]);
    GL16(vS2, &vt[0][d2]);

    const int NT = NLKV / 64;
    for (int t = 0; t < NT; t++) {
        const int cur = t & 1;
        __syncthreads();  // buf[cur] staged (vmcnt drained) + buf[cur^1] free
        if (t + 1 < NT) {
            size_t kvo = (size_t)(t + 1) * 64;
            GL16(kS1 + kvo * NHD, &kt[cur ^ 1][d1]);
            GL16(kS2 + kvo * NHD, &kt[cur ^ 1][d2]);
            GL16(vS1 + kvo, &vt[cur ^ 1][d1]);
            GL16(vS2 + kvo, &vt[cur ^ 1][d2]);
        }
        // mask A-fragments (broadcast rows)
        s16x8 mf[4];
#pragma unroll
        for (int pb = 0; pb < 4; pb++)
            mf[pb] = *(const s16x8*)(mbfb + t * 64 + pb * 16 + hi * 8);

        const u16* ktc = kt[cur];
        const u16* vtc = vt[cur];

        // QK^T swapped: s0 = S^T rows kv 0..31, s1 = rows 32..63; col q = c
        f32x16 s0, s1;
#pragma unroll
        for (int r = 0; r < 16; r++) { s0[r] = 0.f; s1[r] = 0.f; }
        __builtin_amdgcn_s_setprio(1);
#pragma unroll
        for (int kb = 0; kb < 4; kb++) {
            int slot = ((kb * 2 + hi) ^ c7 ^ c3) << 3;
            s16x8 kf0 = *(const s16x8*)&ktc[c * 64 + slot];
            s16x8 kf1 = *(const s16x8*)&ktc[(32 + c) * 64 + slot];
            s0 = __builtin_amdgcn_mfma_f32_32x32x16_bf16(kf0, qa[kb], s0, 0, 0, 0);
            s1 = __builtin_amdgcn_mfma_f32_32x32x16_bf16(kf1, qa[kb], s1, 0, 0, 0);
        }
        __builtin_amdgcn_s_setprio(0);

        // softmax: pure exp2 (Q pre-scaled; mask via V-zeroing + l-MFMA)
        float p0a[16], p1a[16];
#pragma unroll
        for (int r = 0; r < 16; r++) {
            p0a[r] = fast_exp2(s0[r]);
            p1a[r] = fast_exp2(s1[r]);
        }

        // pack to bf16 pairs + permlane swap -> PV B-fragments
        u32 pka[8], pkb2[8];
#pragma unroll
        for (int i = 0; i < 8; i++) {
            pka[i] = pkbf(p0a[2 * i], p0a[2 * i + 1]);
            pkb2[i] = pkbf(p1a[2 * i], p1a[2 * i + 1]);
        }
        pl32swap(pka[0], pka[2]); pl32swap(pka[1], pka[3]);
        pl32swap(pka[4], pka[6]); pl32swap(pka[5], pka[7]);
        pl32swap(pkb2[0], pkb2[2]); pl32swap(pkb2[1], pkb2[3]);
        pl32swap(pkb2[4], pkb2[6]); pl32swap(pkb2[5], pkb2[7]);

        union { u32 u[4]; s16x8 h; } fr[4];
#pragma unroll
        for (int i = 0; i < 4; i++) {
            fr[0].u[i] = pka[i];
            fr[1].u[i] = pka[4 + i];
            fr[2].u[i] = pkb2[i];
            fr[3].u[i] = pkb2[4 + i];
        }

        // PV: O^T[d][q=c] += V^T[d][kv] * P ; l via mask-MFMA on same P frags
        __builtin_amdgcn_s_setprio(1);
#pragma unroll
        for (int pb = 0; pb < 4; pb++) {
            int slot = ((pb * 2 + hi) ^ c7 ^ c3) << 3;
            s16x8 vf0 = *(const s16x8*)&vtc[c * 64 + slot];
            s16x8 vf1 = *(const s16x8*)&vtc[(32 + c) * 64 + slot];
            o0 = __builtin_amdgcn_mfma_f32_32x32x16_bf16(vf0, fr[pb].h, o0, 0, 0, 0);
            o1 = __builtin_amdgcn_mfma_f32_32x32x16_bf16(vf1, fr[pb].h, o1, 0, 0, 0);
            lacc = __builtin_amdgcn_mfma_f32_32x32x16_bf16(mf[pb], fr[pb].h, lacc, 0, 0, 0);
        }
        __builtin_amdgcn_s_setprio(0);
    }

    // lacc rows are all identical = l[q=c] over the full kv range
    float linv = 1.f / lacc[0];

    // epilogue: transpose O through LDS (reuse kt), coalesced global write.
    __syncthreads();
    u32* osh = (u32*)kt + w * 1024;  // per-wave [32 rows][32 dwords]
#pragma unroll
    for (int r = 0; r < 16; r += 2) {
        int d = (r & 3) + 8 * (r >> 2) + 4 * hi;
        u32 plo = pkbf(o0[r] * linv, o0[r + 1] * linv);
        u32 phi = pkbf(o1[r] * linv, o1[r + 1] * linv);
        int dc0 = d >> 1, dc1 = (d + 32) >> 1;
        osh[c * 32 + (((dc0 >> 2) ^ c7) << 2) + (dc0 & 3)] = plo;
        osh[c * 32 + (((dc1 >> 2) ^ c7) << 2) + (dc1 & 3)] = phi;
    }
    __syncthreads();
#pragma unroll
    for (int i = 0; i < 4; i++) {
        int row = 8 * i + (lane >> 3);
        int jj = lane & 7;
        u32 v0 = osh[row * 32 + ((jj ^ (row & 7)) << 2) + 0];
        u32 v1 = osh[row * 32 + ((jj ^ (row & 7)) << 2) + 1];
        u32 v2 = osh[row * 32 + ((jj ^ (row & 7)) << 2) + 2];
        u32 v3 = osh[row * 32 + ((jj ^ (row & 7)) << 2) + 3];
        u32* gp = (u32*)(attn + ((size_t)b * NLQ + qw0 + row) * ND + h * NHD + jj * 8);
        gp[0] = v0; gp[1] = v1; gp[2] = v2; gp[3] = v3;
    }
}

extern "C" void kernel_launch(void* const* d_in, const int* in_sizes, int n_in,
                              void* d_out, int out_size, void* d_ws, size_t ws_size,
                              hipStream_t stream) {
    const float* x_q = (const float*)d_in[0];
    const float* x_kv = (const float*)d_in[1];
    const int* mask = (const int*)d_in[2];
    const float* Wq = (const float*)d_in[3];
    const float* bq = (const float*)d_in[4];
    const float* Wk = (const float*)d_in[5];
    const float* bk = (const float*)d_in[6];
    const float* Wv = (const float*)d_in[7];
    const float* bv = (const float*)d_in[8];
    const float* Wo = (const float*)d_in[9];
    const float* bo = (const float*)d_in[10];
    float* out = (float*)d_out;

    size_t off = 0;
    auto carve = [&](size_t bytes) {
        void* p = (char*)d_ws + off;
        off += (bytes + 255) & ~(size_t)255;
        return p;
    };
    u16* xq_bf = (u16*)carve((size_t)NB * NLQ * ND * 2);
    u16* xkv_bf = (u16*)carve((size_t)NB * NLKV * ND * 2);
    u16* wq_t = (u16*)carve((size_t)ND * ND * 2);
    u16* wkv_t = (u16*)carve((size_t)2 * ND * ND * 2);
    u16* wo_t = (u16*)carve((size_t)ND * ND * 2);
    u16* Qh = (u16*)carve((size_t)NB * NH * NLQ * NHD * 2);
    u16* Kh = (u16*)carve((size_t)NB * NH * NLKV * NHD * 2);
    u16* VTh = (u16*)carve((size_t)NB * NH * NLKV * NHD * 2);
    u16* attn_bf = (u16*)carve((size_t)NB * NLQ * ND * 2);
    u16* mbfw = (u16*)carve((size_t)NB * NLKV * 2);

    prep_kernel<<<dim3(10272), 256, 0, stream>>>(
        x_q, x_kv, mask, Wq, Wk, Wv, Wo,
        xq_bf, xkv_bf, mbfw, wq_t, wkv_t, wkv_t + (size_t)ND * ND, wo_t);
    qkv_kernel<<<dim3(1280), 512, 0, stream>>>(xq_bf, xkv_bf, wq_t, wkv_t,
                                               bq, bk, bv, mask, Qh, Kh, VTh);
    attn_kernel<<<dim3(16, 32), 256, 0, stream>>>(Qh, Kh, VTh, mbfw, attn_bf);
    ogemm_kernel<<<dim3(64, 8), 256, 0, stream>>>(attn_bf, wo_t, bo, out);
}

// Round 19
// 200.221 us; speedup vs baseline: 1.1748x; 1.0739x over previous
//
#include <hip/hip_runtime.h>
#include <hip/hip_bf16.h>

typedef unsigned short u16;
typedef unsigned int u32;
typedef __attribute__((ext_vector_type(8))) unsigned short u16x8;
typedef __attribute__((ext_vector_type(8))) short s16x8;
typedef __attribute__((ext_vector_type(4))) float f32x4;
typedef __attribute__((ext_vector_type(16))) float f32x16;

#define NB 2
#define NLQ 2048
#define NLKV 4096
#define ND 1024
#define NH 16
#define NHD 64
#define SCALE 0.125f
#define QSC (SCALE * 1.44269504f)  // fold scale+log2e into Q

// async global->LDS, 16B per lane; dest = uniform base + lane*16
#define GL16(g, l)                                                            \
    __builtin_amdgcn_global_load_lds(                                         \
        (const __attribute__((address_space(1))) void*)(g),                   \
        (__attribute__((address_space(3))) void*)(l), 16, 0, 0)

__device__ __forceinline__ u16 f2bf(float f) {
    __hip_bfloat16 h = __float2bfloat16(f);
    return *(u16*)&h;
}

__device__ __forceinline__ float fast_exp2(float x) {
    float r;
    asm("v_exp_f32 %0, %1" : "=v"(r) : "v"(x));
    return r;
}

__device__ __forceinline__ u32 pkbf(float lo, float hi_) {
    u32 r;
    asm("v_cvt_pk_bf16_f32 %0, %1, %2" : "=v"(r) : "v"(lo), "v"(hi_));
    return r;
}

// vdst.hi32lanes <-> vsrc.lo32lanes
__device__ __forceinline__ void pl32swap(u32& a, u32& b) {
    asm("v_permlane32_swap_b32 %0, %1" : "+v"(a), "+v"(b));
}

// ---------- unified prep: x f32->bf16 | mask->bf16 | 4x weight transpose ----------
// blocks [0,6144): x convert; [6144,6176): mask; [6176,10272): tcvt (flat-indexed)
__global__ __launch_bounds__(256) void prep_kernel(
    const float* __restrict__ xq, const float* __restrict__ xkv,
    const int* __restrict__ mask,
    const float* __restrict__ w0, const float* __restrict__ w1,
    const float* __restrict__ w2, const float* __restrict__ w3,
    u16* __restrict__ oq, u16* __restrict__ okv, u16* __restrict__ mbf,
    u16* __restrict__ o0, u16* __restrict__ o1,
    u16* __restrict__ o2, u16* __restrict__ o3) {
    __shared__ float t[32][33];
    const int bid = blockIdx.x;
    const int tid = threadIdx.x;
    if (bid < 6144) {
        const float* in;
        u16* out;
        int i0;
        if (bid < 2048) { in = xq; out = oq; i0 = bid; }
        else { in = xkv; out = okv; i0 = bid - 2048; }
        int i = i0 * 256 + tid;
        const float4* p = (const float4*)in;
        float4 a = p[2 * i], b = p[2 * i + 1];
        u16x8 o;
        o[0] = f2bf(a.x); o[1] = f2bf(a.y); o[2] = f2bf(a.z); o[3] = f2bf(a.w);
        o[4] = f2bf(b.x); o[5] = f2bf(b.y); o[6] = f2bf(b.z); o[7] = f2bf(b.w);
        ((u16x8*)out)[i] = o;
        return;
    }
    if (bid < 6176) {
        int g = (bid - 6144) * 256 + tid;
        mbf[g] = mask[g] ? 0x3F80 : 0;  // bf16 1.0
        return;
    }
    // weight transpose: W[k][n] f32 -> Wt[n][k] bf16
    int tb = bid - 6176;
    int z = tb >> 10;
    int rem = tb & 1023;
    int n0 = (rem & 31) * 32, k0 = (rem >> 5) * 32;
    const float* w = z == 0 ? w0 : z == 1 ? w1 : z == 2 ? w2 : w3;
    u16* o = z == 0 ? o0 : z == 1 ? o1 : z == 2 ? o2 : o3;
    int tx = tid & 31, ty = tid >> 5;
#pragma unroll
    for (int i = 0; i < 4; i++) t[ty + 8 * i][tx] = w[(k0 + ty + 8 * i) * ND + n0 + tx];
    __syncthreads();
#pragma unroll
    for (int i = 0; i < 4; i++) o[(n0 + ty + 8 * i) * ND + k0 + tx] = f2bf(t[tx][ty + 8 * i]);
}

// ---------- unified QKV projection GEMM v3: BK=64 + XOR-swizzled LDS ----------
// 1280 blocks (256 Q + 1024 KV), XCD-bijective swizzle, 512 thr = 8 waves 2x4.
// As/Bs = [128][64] u16 (32 KB); LDS slot j of row r holds logical chunk
// j ^ (r&7) via pre-swizzled GL16 source -> conflict-free fragment reads.
// 16 iterations x 1 barrier-pair (was 32). V-half blocks swap MFMA operands.
__global__ __launch_bounds__(512) void qkv_kernel(
    const u16* __restrict__ xq, const u16* __restrict__ xkv,
    const u16* __restrict__ wq_t, const u16* __restrict__ wkv_t,
    const float* __restrict__ bq, const float* __restrict__ bk,
    const float* __restrict__ bv, const int* __restrict__ vmask,
    u16* __restrict__ Qh, u16* __restrict__ Kh, u16* __restrict__ VTh) {
    const int bid = blockIdx.x;
    const int swz = (bid & 7) * 160 + (bid >> 3);
    const bool isQ = swz < 256;
    int m0, n0;
    const u16 *A, *Bt;
    if (isQ) {
        m0 = (swz >> 3) * 128; n0 = (swz & 7) * 128;
        A = xq; Bt = wq_t;
    } else {
        int t2 = swz - 256;
        m0 = (t2 >> 4) * 128; n0 = (t2 & 15) * 128;
        A = xkv; Bt = wkv_t;
    }
    const bool isV = !isQ && n0 >= 1024;

    __shared__ __align__(16) u16 As[128 * 64];
    __shared__ __align__(16) u16 Bs[128 * 64];
    const int tid = threadIdx.x;
    const int lane = tid & 63, w = tid >> 6;
    const int wr = w >> 2, wc = w & 3;
    const int lr = lane & 15, lg = lane >> 4;
    const int l7 = lr & 7;

    f32x4 acc[4][2];
#pragma unroll
    for (int i = 0; i < 4; i++)
#pragma unroll
        for (int j = 0; j < 2; j++)
#pragma unroll
            for (int r = 0; r < 4; r++) acc[i][j][r] = 0.f;

    // staging: thread covers (row srow, slot sj) and (row srow+64, slot sj);
    // slot j holds logical chunk j ^ (row&7); (srow+64)&7 == srow&7.
    const int srow = tid >> 3, sj = tid & 7;
    const int sx8 = (sj ^ (srow & 7)) * 8;
    const u16* Ag1 = A + (size_t)(m0 + srow) * ND + sx8;
    const u16* Ag2 = A + (size_t)(m0 + 64 + srow) * ND + sx8;
    const u16* Bg1 = Bt + (size_t)(n0 + srow) * ND + sx8;
    const u16* Bg2 = Bt + (size_t)(n0 + 64 + srow) * ND + sx8;
    u16* lA1 = &As[w * 512];
    u16* lA2 = &As[4096 + w * 512];
    u16* lB1 = &Bs[w * 512];
    u16* lB2 = &Bs[4096 + w * 512];

    for (int kt = 0; kt < ND; kt += 64) {
        GL16(Ag1 + kt, lA1);
        GL16(Ag2 + kt, lA2);
        GL16(Bg1 + kt, lB1);
        GL16(Bg2 + kt, lB2);
        __syncthreads();

#pragma unroll
        for (int kk = 0; kk < 2; kk++) {
            const int slot = ((kk * 4 + lg) ^ l7) * 8;
            s16x8 af[4], bf[2];
#pragma unroll
            for (int i = 0; i < 4; i++)
                af[i] = *(const s16x8*)&As[(wr * 64 + i * 16 + lr) * 64 + slot];
#pragma unroll
            for (int j = 0; j < 2; j++)
                bf[j] = *(const s16x8*)&Bs[(wc * 32 + j * 16 + lr) * 64 + slot];
            if (isV) {
#pragma unroll
                for (int mi = 0; mi < 4; mi++)
#pragma unroll
                    for (int ni = 0; ni < 2; ni++)
                        acc[mi][ni] = __builtin_amdgcn_mfma_f32_16x16x32_bf16(
                            bf[ni], af[mi], acc[mi][ni], 0, 0, 0);
            } else {
#pragma unroll
                for (int mi = 0; mi < 4; mi++)
#pragma unroll
                    for (int ni = 0; ni < 2; ni++)
                        acc[mi][ni] = __builtin_amdgcn_mfma_f32_16x16x32_bf16(
                            af[mi], bf[ni], acc[mi][ni], 0, 0, 0);
            }
        }
        __syncthreads();
    }

#pragma unroll
    for (int mi = 0; mi < 4; mi++)
#pragma unroll
        for (int ni = 0; ni < 2; ni++)
#pragma unroll
            for (int r = 0; r < 4; r++) {
                if (isQ) {
                    int m = m0 + wr * 64 + mi * 16 + lg * 4 + r;
                    int n = n0 + wc * 32 + ni * 16 + lr;
                    int h = n >> 6, d = n & 63;
                    int b = m >> 11, lq = m & 2047;
                    Qh[((((size_t)b * NH + h) * NLQ + lq) << 6) + d] =
                        f2bf((acc[mi][ni][r] + bq[n]) * QSC);
                } else if (!isV) {
                    int m = m0 + wr * 64 + mi * 16 + lg * 4 + r;
                    int n = n0 + wc * 32 + ni * 16 + lr;
                    int h = n >> 6, d = n & 63;
                    int b = m >> 12, lkv = m & 4095;
                    Kh[((((size_t)b * NH + h) * NLKV + lkv) << 6) + d] =
                        f2bf(acc[mi][ni][r] + bk[n]);
                } else {
                    // transposed acc: row = n2 (d-dim), col = m (lkv, 16 consecutive)
                    int n2 = (n0 - 1024) + wc * 32 + ni * 16 + lg * 4 + r;
                    int m = m0 + wr * 64 + mi * 16 + lr;
                    int h = n2 >> 6, d = n2 & 63;
                    int b = m >> 12, lkv = m & 4095;
                    float val = vmask[(size_t)b * NLKV + lkv]
                                    ? acc[mi][ni][r] + bv[n2] : 0.f;
                    VTh[(((size_t)b * NH + h) * NHD + d) * NLKV + lkv] = f2bf(val);
                }
            }
}

// ---------- O-projection GEMM (f32 out), 64x128 tile -> 512 blocks (2/CU) ----------
__global__ __launch_bounds__(256) void ogemm_kernel(
    const u16* __restrict__ A, const u16* __restrict__ Bt,
    const float* __restrict__ bias, float* __restrict__ Cout) {
    __shared__ __align__(16) u16 As[64 * 32];
    __shared__ __align__(16) u16 Bs[128 * 32];
    const int m0 = blockIdx.x * 64;
    const int n0 = blockIdx.y * 128;
    const int tid = threadIdx.x;
    const int lane = tid & 63, w = tid >> 6;
    const int wr = w >> 1, wc = w & 1;  // 2x2 wave grid
    const int lr = lane & 15, lg = lane >> 4;
    const int ko = lg * 8;

    f32x4 acc[2][4];
#pragma unroll
    for (int i = 0; i < 2; i++)
#pragma unroll
        for (int j = 0; j < 4; j++)
#pragma unroll
            for (int r = 0; r < 4; r++) acc[i][j][r] = 0.f;

    const int srow = tid >> 2, spart = tid & 3;
    const u16* Ag = A + (size_t)(m0 + srow) * ND + spart * 8;
    const u16* Bg = Bt + (size_t)(n0 + srow) * ND + spart * 8;
    const u16* Bg2 = Bt + (size_t)(n0 + 64 + srow) * ND + spart * 8;
    u16* lA = &As[w * 512];
    u16* lB = &Bs[w * 512];
    u16* lB2 = &Bs[2048 + w * 512];

    for (int kt = 0; kt < ND; kt += 32) {
        GL16(Ag + kt, lA);
        GL16(Bg + kt, lB);
        GL16(Bg2 + kt, lB2);
        __syncthreads();

        s16x8 af[2], bf[4];
#pragma unroll
        for (int i = 0; i < 2; i++)
            af[i] = *(const s16x8*)&As[(wr * 32 + i * 16 + lr) * 32 + ko];
#pragma unroll
        for (int j = 0; j < 4; j++)
            bf[j] = *(const s16x8*)&Bs[(wc * 64 + j * 16 + lr) * 32 + ko];
#pragma unroll
        for (int mi = 0; mi < 2; mi++)
#pragma unroll
            for (int ni = 0; ni < 4; ni++)
                acc[mi][ni] = __builtin_amdgcn_mfma_f32_16x16x32_bf16(
                    af[mi], bf[ni], acc[mi][ni], 0, 0, 0);
        __syncthreads();
    }

#pragma unroll
    for (int mi = 0; mi < 2; mi++)
#pragma unroll
        for (int ni = 0; ni < 4; ni++)
#pragma unroll
            for (int r = 0; r < 4; r++) {
                int m = m0 + wr * 32 + mi * 16 + lg * 4 + r;
                int n = n0 + wc * 64 + ni * 16 + lr;
                Cout[(size_t)m * ND + n] = acc[mi][ni][r] + bias[n];
            }
}

// ---------- flash attention (R16-proven): swapped QK^T + setprio + swizzles ----------
__global__ __launch_bounds__(256) void attn_kernel(
    const u16* __restrict__ Qh, const u16* __restrict__ Kh,
    const u16* __restrict__ VTh, const u16* __restrict__ mbf,
    u16* __restrict__ attn) {
    const int l = blockIdx.x + 16 * blockIdx.y;
    const int qt = l >> 5;
    const int bh = (l & 7) * 4 + ((l >> 3) & 3);
    const int b = bh >> 4, h = bh & 15;
    const int tid = threadIdx.x;
    const int lane = tid & 63, w = tid >> 6;
    const int c = lane & 31, hi = lane >> 5;
    const int c7 = c & 7, c3 = (c >> 3) & 3;

    __shared__ __align__(16) u16 kt[2][4096];
    __shared__ __align__(16) u16 vt[2][4096];

    const int qw0 = qt * 128 + w * 32;
    const u16* Qb = Qh + (size_t)bh * NLQ * NHD;
    const u16* Kb = Kh + (size_t)bh * NLKV * NHD;
    const u16* VTb = VTh + (size_t)bh * NHD * NLKV;
    const u16* mbfb = mbf + (size_t)b * NLKV;

    // Q B-fragments: lane holds Q[qw0+c][kb*16 + hi*8 .. +7]
    s16x8 qa[4];
#pragma unroll
    for (int kb = 0; kb < 4; kb++)
        qa[kb] = *(const s16x8*)(Qb + (size_t)(qw0 + c) * NHD + kb * 16 + hi * 8);

    f32x16 o0, o1, lacc;
#pragma unroll
    for (int r = 0; r < 16; r++) { o0[r] = 0.f; o1[r] = 0.f; lacc[r] = 0.f; }

    // staging: row srow & srow+32, chunk sj; slot j holds logical chunk
    // j ^ (row&7) ^ ((row>>3)&3)   (key(row+32) == key(row))
    const int srow = 8 * w + (lane >> 3);
    const int sj = lane & 7;
    const int sx8 = (sj ^ (srow & 7) ^ ((srow >> 3) & 3)) * 8;
    const u16* kS1 = Kb + (size_t)srow * NHD + sx8;
    const u16* kS2 = Kb + (size_t)(srow + 32) * NHD + sx8;
    const u16* vS1 = VTb + (size_t)srow * NLKV + sx8;
    const u16* vS2 = VTb + (size_t)(srow + 32) * NLKV + sx8;
    const int d1 = w * 512, d2 = 2048 + w * 512;

    // prologue: stage tile 0 into buffer 0
    GL16(kS1, &kt[0][d1]);
    GL16(kS2, &kt[0][d2]);
    GL16(vS1, &vt[0][d1]);
    GL16(vS2, &vt[0][d2]);

    const int NT = NLKV / 64;
    for (int t = 0; t < NT; t++) {
        const int cur = t & 1;
        __syncthreads();  // buf[cur] staged (vmcnt drained) + buf[cur^1] free
        if (t + 1 < NT) {
            size_t kvo = (size_t)(t + 1) * 64;
            GL16(kS1 + kvo * NHD, &kt[cur ^ 1][d1]);
            GL16(kS2 + kvo * NHD, &kt[cur ^ 1][d2]);
            GL16(vS1 + kvo, &vt[cur ^ 1][d1]);
            GL16(vS2 + kvo, &vt[cur ^ 1][d2]);
        }
        // mask A-fragments (broadcast rows)
        s16x8 mf[4];
#pragma unroll
        for (int pb = 0; pb < 4; pb++)
            mf[pb] = *(const s16x8*)(mbfb + t * 64 + pb * 16 + hi * 8);

        const u16* ktc = kt[cur];
        const u16* vtc = vt[cur];

        // QK^T swapped: s0 = S^T rows kv 0..31, s1 = rows 32..63; col q = c
        f32x16 s0, s1;
#pragma unroll
        for (int r = 0; r < 16; r++) { s0[r] = 0.f; s1[r] = 0.f; }
        __builtin_amdgcn_s_setprio(1);
#pragma unroll
        for (int kb = 0; kb < 4; kb++) {
            int slot = ((kb * 2 + hi) ^ c7 ^ c3) << 3;
            s16x8 kf0 = *(const s16x8*)&ktc[c * 64 + slot];
            s16x8 kf1 = *(const s16x8*)&ktc[(32 + c) * 64 + slot];
            s0 = __builtin_amdgcn_mfma_f32_32x32x16_bf16(kf0, qa[kb], s0, 0, 0, 0);
            s1 = __builtin_amdgcn_mfma_f32_32x32x16_bf16(kf1, qa[kb], s1, 0, 0, 0);
        }
        __builtin_amdgcn_s_setprio(0);

        // softmax: pure exp2 (Q pre-scaled; mask via V-zeroing + l-MFMA)
        float p0a[16], p1a[16];
#pragma unroll
        for (int r = 0; r < 16; r++) {
            p0a[r] = fast_exp2(s0[r]);
            p1a[r] = fast_exp2(s1[r]);
        }

        // pack to bf16 pairs + permlane swap -> PV B-fragments
        u32 pka[8], pkb2[8];
#pragma unroll
        for (int i = 0; i < 8; i++) {
            pka[i] = pkbf(p0a[2 * i], p0a[2 * i + 1]);
            pkb2[i] = pkbf(p1a[2 * i], p1a[2 * i + 1]);
        }
        pl32swap(pka[0], pka[2]); pl32swap(pka[1], pka[3]);
        pl32swap(pka[4], pka[6]); pl32swap(pka[5], pka[7]);
        pl32swap(pkb2[0], pkb2[2]); pl32swap(pkb2[1], pkb2[3]);
        pl32swap(pkb2[4], pkb2[6]); pl32swap(pkb2[5], pkb2[7]);

        union { u32 u[4]; s16x8 h; } fr[4];
#pragma unroll
        for (int i = 0; i < 4; i++) {
            fr[0].u[i] = pka[i];
            fr[1].u[i] = pka[4 + i];
            fr[2].u[i] = pkb2[i];
            fr[3].u[i] = pkb2[4 + i];
        }

        // PV: O^T[d][q=c] += V^T[d][kv] * P ; l via mask-MFMA on same P frags
        __builtin_amdgcn_s_setprio(1);
#pragma unroll
        for (int pb = 0; pb < 4; pb++) {
            int slot = ((pb * 2 + hi) ^ c7 ^ c3) << 3;
            s16x8 vf0 = *(const s16x8*)&vtc[c * 64 + slot];
            s16x8 vf1 = *(const s16x8*)&vtc[(32 + c) * 64 + slot];
            o0 = __builtin_amdgcn_mfma_f32_32x32x16_bf16(vf0, fr[pb].h, o0, 0, 0, 0);
            o1 = __builtin_amdgcn_mfma_f32_32x32x16_bf16(vf1, fr[pb].h, o1, 0, 0, 0);
            lacc = __builtin_amdgcn_mfma_f32_32x32x16_bf16(mf[pb], fr[pb].h, lacc, 0, 0, 0);
        }
        __builtin_amdgcn_s_setprio(0);
    }

    // lacc rows are all identical = l[q=c] over the full kv range
    float linv = 1.f / lacc[0];

    // epilogue: transpose O through LDS (reuse kt), coalesced global write.
    __syncthreads();
    u32* osh = (u32*)kt + w * 1024;  // per-wave [32 rows][32 dwords]
#pragma unroll
    for (int r = 0; r < 16; r += 2) {
        int d = (r & 3) + 8 * (r >> 2) + 4 * hi;
        u32 plo = pkbf(o0[r] * linv, o0[r + 1] * linv);
        u32 phi = pkbf(o1[r] * linv, o1[r + 1] * linv);
        int dc0 = d >> 1, dc1 = (d + 32) >> 1;
        osh[c * 32 + (((dc0 >> 2) ^ c7) << 2) + (dc0 & 3)] = plo;
        osh[c * 32 + (((dc1 >> 2) ^ c7) << 2) + (dc1 & 3)] = phi;
    }
    __syncthreads();
#pragma unroll
    for (int i = 0; i < 4; i++) {
        int row = 8 * i + (lane >> 3);
        int jj = lane & 7;
        u32 v0 = osh[row * 32 + ((jj ^ (row & 7)) << 2) + 0];
        u32 v1 = osh[row * 32 + ((jj ^ (row & 7)) << 2) + 1];
        u32 v2 = osh[row * 32 + ((jj ^ (row & 7)) << 2) + 2];
        u32 v3 = osh[row * 32 + ((jj ^ (row & 7)) << 2) + 3];
        u32* gp = (u32*)(attn + ((size_t)b * NLQ + qw0 + row) * ND + h * NHD + jj * 8);
        gp[0] = v0; gp[1] = v1; gp[2] = v2; gp[3] = v3;
    }
}

extern "C" void kernel_launch(void* const* d_in, const int* in_sizes, int n_in,
                              void* d_out, int out_size, void* d_ws, size_t ws_size,
                              hipStream_t stream) {
    const float* x_q = (const float*)d_in[0];
    const float* x_kv = (const float*)d_in[1];
    const int* mask = (const int*)d_in[2];
    const float* Wq = (const float*)d_in[3];
    const float* bq = (const float*)d_in[4];
    const float* Wk = (const float*)d_in[5];
    const float* bk = (const float*)d_in[6];
    const float* Wv = (const float*)d_in[7];
    const float* bv = (const float*)d_in[8];
    const float* Wo = (const float*)d_in[9];
    const float* bo = (const float*)d_in[10];
    float* out = (float*)d_out;

    size_t off = 0;
    auto carve = [&](size_t bytes) {
        void* p = (char*)d_ws + off;
        off += (bytes + 255) & ~(size_t)255;
        return p;
    };
    u16* xq_bf = (u16*)carve((size_t)NB * NLQ * ND * 2);
    u16* xkv_bf = (u16*)carve((size_t)NB * NLKV * ND * 2);
    u16* wq_t = (u16*)carve((size_t)ND * ND * 2);
    u16* wkv_t = (u16*)carve((size_t)2 * ND * ND * 2);
    u16* wo_t = (u16*)carve((size_t)ND * ND * 2);
    u16* Qh = (u16*)carve((size_t)NB * NH * NLQ * NHD * 2);
    u16* Kh = (u16*)carve((size_t)NB * NH * NLKV * NHD * 2);
    u16* VTh = (u16*)carve((size_t)NB * NH * NLKV * NHD * 2);
    u16* attn_bf = (u16*)carve((size_t)NB * NLQ * ND * 2);
    u16* mbfw = (u16*)carve((size_t)NB * NLKV * 2);

    prep_kernel<<<dim3(10272), 256, 0, stream>>>(
        x_q, x_kv, mask, Wq, Wk, Wv, Wo,
        xq_bf, xkv_bf, mbfw, wq_t, wkv_t, wkv_t + (size_t)ND * ND, wo_t);
    qkv_kernel<<<dim3(1280), 512, 0, stream>>>(xq_bf, xkv_bf, wq_t, wkv_t,
                                               bq, bk, bv, mask, Qh, Kh, VTh);
    attn_kernel<<<dim3(16, 32), 256, 0, stream>>>(Qh, Kh, VTh, mbfw, attn_bf);
    ogemm_kernel<<<dim3(64, 8), 256, 0, stream>>>(attn_bf, wo_t, bo, out);
}

// Round 20
// 199.474 us; speedup vs baseline: 1.1792x; 1.0037x over previous
//
#include <hip/hip_runtime.h>
#include <hip/hip_bf16.h>

typedef unsigned short u16;
typedef unsigned int u32;
typedef __attribute__((ext_vector_type(8))) unsigned short u16x8;
typedef __attribute__((ext_vector_type(8))) short s16x8;
typedef __attribute__((ext_vector_type(4))) float f32x4;
typedef __attribute__((ext_vector_type(16))) float f32x16;

#define NB 2
#define NLQ 2048
#define NLKV 4096
#define ND 1024
#define NH 16
#define NHD 64
#define SCALE 0.125f
#define QSC (SCALE * 1.44269504f)  // fold scale+log2e into Q

// async global->LDS, 16B per lane; dest = uniform base + lane*16
#define GL16(g, l)                                                            \
    __builtin_amdgcn_global_load_lds(                                         \
        (const __attribute__((address_space(1))) void*)(g),                   \
        (__attribute__((address_space(3))) void*)(l), 16, 0, 0)

__device__ __forceinline__ u16 f2bf(float f) {
    __hip_bfloat16 h = __float2bfloat16(f);
    return *(u16*)&h;
}

__device__ __forceinline__ float fast_exp2(float x) {
    float r;
    asm("v_exp_f32 %0, %1" : "=v"(r) : "v"(x));
    return r;
}

__device__ __forceinline__ u32 pkbf(float lo, float hi_) {
    u32 r;
    asm("v_cvt_pk_bf16_f32 %0, %1, %2" : "=v"(r) : "v"(lo), "v"(hi_));
    return r;
}

// vdst.hi32lanes <-> vsrc.lo32lanes
__device__ __forceinline__ void pl32swap(u32& a, u32& b) {
    asm("v_permlane32_swap_b32 %0, %1" : "+v"(a), "+v"(b));
}

// ---------- unified prep: x f32->bf16 | mask->bf16 | 4x weight transpose ----------
__global__ __launch_bounds__(256) void prep_kernel(
    const float* __restrict__ xq, const float* __restrict__ xkv,
    const int* __restrict__ mask,
    const float* __restrict__ w0, const float* __restrict__ w1,
    const float* __restrict__ w2, const float* __restrict__ w3,
    u16* __restrict__ oq, u16* __restrict__ okv, u16* __restrict__ mbf,
    u16* __restrict__ o0, u16* __restrict__ o1,
    u16* __restrict__ o2, u16* __restrict__ o3) {
    __shared__ float t[32][33];
    const int bid = blockIdx.x;
    const int tid = threadIdx.x;
    if (bid < 6144) {
        const float* in;
        u16* out;
        int i0;
        if (bid < 2048) { in = xq; out = oq; i0 = bid; }
        else { in = xkv; out = okv; i0 = bid - 2048; }
        int i = i0 * 256 + tid;
        const float4* p = (const float4*)in;
        float4 a = p[2 * i], b = p[2 * i + 1];
        u16x8 o;
        o[0] = f2bf(a.x); o[1] = f2bf(a.y); o[2] = f2bf(a.z); o[3] = f2bf(a.w);
        o[4] = f2bf(b.x); o[5] = f2bf(b.y); o[6] = f2bf(b.z); o[7] = f2bf(b.w);
        ((u16x8*)out)[i] = o;
        return;
    }
    if (bid < 6176) {
        int g = (bid - 6144) * 256 + tid;
        mbf[g] = mask[g] ? 0x3F80 : 0;  // bf16 1.0
        return;
    }
    int tb = bid - 6176;
    int z = tb >> 10;
    int rem = tb & 1023;
    int n0 = (rem & 31) * 32, k0 = (rem >> 5) * 32;
    const float* w = z == 0 ? w0 : z == 1 ? w1 : z == 2 ? w2 : w3;
    u16* o = z == 0 ? o0 : z == 1 ? o1 : z == 2 ? o2 : o3;
    int tx = tid & 31, ty = tid >> 5;
#pragma unroll
    for (int i = 0; i < 4; i++) t[ty + 8 * i][tx] = w[(k0 + ty + 8 * i) * ND + n0 + tx];
    __syncthreads();
#pragma unroll
    for (int i = 0; i < 4; i++) o[(n0 + ty + 8 * i) * ND + k0 + tx] = f2bf(t[tx][ty + 8 * i]);
}

// ---------- unified QKV projection GEMM v3 (R19-proven): BK=64 + XOR swizzle ----------
__global__ __launch_bounds__(512) void qkv_kernel(
    const u16* __restrict__ xq, const u16* __restrict__ xkv,
    const u16* __restrict__ wq_t, const u16* __restrict__ wkv_t,
    const float* __restrict__ bq, const float* __restrict__ bk,
    const float* __restrict__ bv, const int* __restrict__ vmask,
    u16* __restrict__ Qh, u16* __restrict__ Kh, u16* __restrict__ VTh) {
    const int bid = blockIdx.x;
    const int swz = (bid & 7) * 160 + (bid >> 3);
    const bool isQ = swz < 256;
    int m0, n0;
    const u16 *A, *Bt;
    if (isQ) {
        m0 = (swz >> 3) * 128; n0 = (swz & 7) * 128;
        A = xq; Bt = wq_t;
    } else {
        int t2 = swz - 256;
        m0 = (t2 >> 4) * 128; n0 = (t2 & 15) * 128;
        A = xkv; Bt = wkv_t;
    }
    const bool isV = !isQ && n0 >= 1024;

    __shared__ __align__(16) u16 As[128 * 64];
    __shared__ __align__(16) u16 Bs[128 * 64];
    const int tid = threadIdx.x;
    const int lane = tid & 63, w = tid >> 6;
    const int wr = w >> 2, wc = w & 3;
    const int lr = lane & 15, lg = lane >> 4;
    const int l7 = lr & 7;

    f32x4 acc[4][2];
#pragma unroll
    for (int i = 0; i < 4; i++)
#pragma unroll
        for (int j = 0; j < 2; j++)
#pragma unroll
            for (int r = 0; r < 4; r++) acc[i][j][r] = 0.f;

    const int srow = tid >> 3, sj = tid & 7;
    const int sx8 = (sj ^ (srow & 7)) * 8;
    const u16* Ag1 = A + (size_t)(m0 + srow) * ND + sx8;
    const u16* Ag2 = A + (size_t)(m0 + 64 + srow) * ND + sx8;
    const u16* Bg1 = Bt + (size_t)(n0 + srow) * ND + sx8;
    const u16* Bg2 = Bt + (size_t)(n0 + 64 + srow) * ND + sx8;
    u16* lA1 = &As[w * 512];
    u16* lA2 = &As[4096 + w * 512];
    u16* lB1 = &Bs[w * 512];
    u16* lB2 = &Bs[4096 + w * 512];

    for (int kt = 0; kt < ND; kt += 64) {
        GL16(Ag1 + kt, lA1);
        GL16(Ag2 + kt, lA2);
        GL16(Bg1 + kt, lB1);
        GL16(Bg2 + kt, lB2);
        __syncthreads();

#pragma unroll
        for (int kk = 0; kk < 2; kk++) {
            const int slot = ((kk * 4 + lg) ^ l7) * 8;
            s16x8 af[4], bf[2];
#pragma unroll
            for (int i = 0; i < 4; i++)
                af[i] = *(const s16x8*)&As[(wr * 64 + i * 16 + lr) * 64 + slot];
#pragma unroll
            for (int j = 0; j < 2; j++)
                bf[j] = *(const s16x8*)&Bs[(wc * 32 + j * 16 + lr) * 64 + slot];
            if (isV) {
#pragma unroll
                for (int mi = 0; mi < 4; mi++)
#pragma unroll
                    for (int ni = 0; ni < 2; ni++)
                        acc[mi][ni] = __builtin_amdgcn_mfma_f32_16x16x32_bf16(
                            bf[ni], af[mi], acc[mi][ni], 0, 0, 0);
            } else {
#pragma unroll
                for (int mi = 0; mi < 4; mi++)
#pragma unroll
                    for (int ni = 0; ni < 2; ni++)
                        acc[mi][ni] = __builtin_amdgcn_mfma_f32_16x16x32_bf16(
                            af[mi], bf[ni], acc[mi][ni], 0, 0, 0);
            }
        }
        __syncthreads();
    }

#pragma unroll
    for (int mi = 0; mi < 4; mi++)
#pragma unroll
        for (int ni = 0; ni < 2; ni++)
#pragma unroll
            for (int r = 0; r < 4; r++) {
                if (isQ) {
                    int m = m0 + wr * 64 + mi * 16 + lg * 4 + r;
                    int n = n0 + wc * 32 + ni * 16 + lr;
                    int h = n >> 6, d = n & 63;
                    int b = m >> 11, lq = m & 2047;
                    Qh[((((size_t)b * NH + h) * NLQ + lq) << 6) + d] =
                        f2bf((acc[mi][ni][r] + bq[n]) * QSC);
                } else if (!isV) {
                    int m = m0 + wr * 64 + mi * 16 + lg * 4 + r;
                    int n = n0 + wc * 32 + ni * 16 + lr;
                    int h = n >> 6, d = n & 63;
                    int b = m >> 12, lkv = m & 4095;
                    Kh[((((size_t)b * NH + h) * NLKV + lkv) << 6) + d] =
                        f2bf(acc[mi][ni][r] + bk[n]);
                } else {
                    int n2 = (n0 - 1024) + wc * 32 + ni * 16 + lg * 4 + r;
                    int m = m0 + wr * 64 + mi * 16 + lr;
                    int h = n2 >> 6, d = n2 & 63;
                    int b = m >> 12, lkv = m & 4095;
                    float val = vmask[(size_t)b * NLKV + lkv]
                                    ? acc[mi][ni][r] + bv[n2] : 0.f;
                    VTh[(((size_t)b * NH + h) * NHD + d) * NLKV + lkv] = f2bf(val);
                }
            }
}

// ---------- O-projection GEMM v2: 64x128 tile, BK=64 + XOR swizzle ----------
// 512 blocks (2/CU), 256 thr = 4 waves 2x2. As[64][64], Bs[128][64] (24 KB).
// 16 barrier-pairs (was 32); conflict-free fragment reads (R19 qkv recipe).
__global__ __launch_bounds__(256) void ogemm_kernel(
    const u16* __restrict__ A, const u16* __restrict__ Bt,
    const float* __restrict__ bias, float* __restrict__ Cout) {
    __shared__ __align__(16) u16 As[64 * 64];
    __shared__ __align__(16) u16 Bs[128 * 64];
    const int m0 = blockIdx.x * 64;
    const int n0 = blockIdx.y * 128;
    const int tid = threadIdx.x;
    const int lane = tid & 63, w = tid >> 6;
    const int wr = w >> 1, wc = w & 1;  // 2x2 wave grid
    const int lr = lane & 15, lg = lane >> 4;
    const int l7 = lr & 7;

    f32x4 acc[2][4];
#pragma unroll
    for (int i = 0; i < 2; i++)
#pragma unroll
        for (int j = 0; j < 4; j++)
#pragma unroll
            for (int r = 0; r < 4; r++) acc[i][j][r] = 0.f;

    // staging: slot sj of row r holds logical chunk sj ^ (r&7); rows r, r+32(,+64,+96)
    const int srow = tid >> 3, sj = tid & 7;
    const int sx8 = (sj ^ (srow & 7)) * 8;
    const u16* Ag1 = A + (size_t)(m0 + srow) * ND + sx8;
    const u16* Ag2 = A + (size_t)(m0 + 32 + srow) * ND + sx8;
    const u16* Bg1 = Bt + (size_t)(n0 + srow) * ND + sx8;
    const u16* Bg2 = Bt + (size_t)(n0 + 32 + srow) * ND + sx8;
    const u16* Bg3 = Bt + (size_t)(n0 + 64 + srow) * ND + sx8;
    const u16* Bg4 = Bt + (size_t)(n0 + 96 + srow) * ND + sx8;
    u16* lA1 = &As[w * 512];
    u16* lA2 = &As[2048 + w * 512];
    u16* lB1 = &Bs[w * 512];
    u16* lB2 = &Bs[2048 + w * 512];
    u16* lB3 = &Bs[4096 + w * 512];
    u16* lB4 = &Bs[6144 + w * 512];

    for (int kt = 0; kt < ND; kt += 64) {
        GL16(Ag1 + kt, lA1);
        GL16(Ag2 + kt, lA2);
        GL16(Bg1 + kt, lB1);
        GL16(Bg2 + kt, lB2);
        GL16(Bg3 + kt, lB3);
        GL16(Bg4 + kt, lB4);
        __syncthreads();

#pragma unroll
        for (int kk = 0; kk < 2; kk++) {
            const int slot = ((kk * 4 + lg) ^ l7) * 8;
            s16x8 af[2], bf[4];
#pragma unroll
            for (int i = 0; i < 2; i++)
                af[i] = *(const s16x8*)&As[(wr * 32 + i * 16 + lr) * 64 + slot];
#pragma unroll
            for (int j = 0; j < 4; j++)
                bf[j] = *(const s16x8*)&Bs[(wc * 64 + j * 16 + lr) * 64 + slot];
#pragma unroll
            for (int mi = 0; mi < 2; mi++)
#pragma unroll
                for (int ni = 0; ni < 4; ni++)
                    acc[mi][ni] = __builtin_amdgcn_mfma_f32_16x16x32_bf16(
                        af[mi], bf[ni], acc[mi][ni], 0, 0, 0);
        }
        __syncthreads();
    }

#pragma unroll
    for (int mi = 0; mi < 2; mi++)
#pragma unroll
        for (int ni = 0; ni < 4; ni++)
#pragma unroll
            for (int r = 0; r < 4; r++) {
                int m = m0 + wr * 32 + mi * 16 + lg * 4 + r;
                int n = n0 + wc * 64 + ni * 16 + lr;
                Cout[(size_t)m * ND + n] = acc[mi][ni][r] + bias[n];
            }
}

// ---------- flash attention: R16 body + per-half softmax/PV interleave ----------
// Reorder only: exp/pack(s0) -> PV(pb 0-1) -> exp/pack(s1) -> PV(pb 2-3) so
// PV(0-1) MFMAs overlap exp2(s1) VALU (the busiest pipe). Same math/registers.
__global__ __launch_bounds__(256) void attn_kernel(
    const u16* __restrict__ Qh, const u16* __restrict__ Kh,
    const u16* __restrict__ VTh, const u16* __restrict__ mbf,
    u16* __restrict__ attn) {
    const int l = blockIdx.x + 16 * blockIdx.y;
    const int qt = l >> 5;
    const int bh = (l & 7) * 4 + ((l >> 3) & 3);
    const int b = bh >> 4, h = bh & 15;
    const int tid = threadIdx.x;
    const int lane = tid & 63, w = tid >> 6;
    const int c = lane & 31, hi = lane >> 5;
    const int c7 = c & 7, c3 = (c >> 3) & 3;

    __shared__ __align__(16) u16 kt[2][4096];
    __shared__ __align__(16) u16 vt[2][4096];

    const int qw0 = qt * 128 + w * 32;
    const u16* Qb = Qh + (size_t)bh * NLQ * NHD;
    const u16* Kb = Kh + (size_t)bh * NLKV * NHD;
    const u16* VTb = VTh + (size_t)bh * NHD * NLKV;
    const u16* mbfb = mbf + (size_t)b * NLKV;

    s16x8 qa[4];
#pragma unroll
    for (int kb = 0; kb < 4; kb++)
        qa[kb] = *(const s16x8*)(Qb + (size_t)(qw0 + c) * NHD + kb * 16 + hi * 8);

    f32x16 o0, o1, lacc;
#pragma unroll
    for (int r = 0; r < 16; r++) { o0[r] = 0.f; o1[r] = 0.f; lacc[r] = 0.f; }

    const int srow = 8 * w + (lane >> 3);
    const int sj = lane & 7;
    const int sx8 = (sj ^ (srow & 7) ^ ((srow >> 3) & 3)) * 8;
    const u16* kS1 = Kb + (size_t)srow * NHD + sx8;
    const u16* kS2 = Kb + (size_t)(srow + 32) * NHD + sx8;
    const u16* vS1 = VTb + (size_t)srow * NLKV + sx8;
    const u16* vS2 = VTb + (size_t)(srow + 32) * NLKV + sx8;
    const int d1 = w * 512, d2 = 2048 + w * 512;

    GL16(kS1, &kt[0][d1]);
    GL16(kS2, &kt[0][d2]);
    GL16(vS1, &vt[0][d1]);
    GL16(vS2, &vt[0][d2]);

    const int NT = NLKV / 64;
    for (int t = 0; t < NT; t++) {
        const int cur = t & 1;
        __syncthreads();
        if (t + 1 < NT) {
            size_t kvo = (size_t)(t + 1) * 64;
            GL16(kS1 + kvo * NHD, &kt[cur ^ 1][d1]);
            GL16(kS2 + kvo * NHD, &kt[cur ^ 1][d2]);
            GL16(vS1 + kvo, &vt[cur ^ 1][d1]);
            GL16(vS2 + kvo, &vt[cur ^ 1][d2]);
        }
        s16x8 mf[4];
#pragma unroll
        for (int pb = 0; pb < 4; pb++)
            mf[pb] = *(const s16x8*)(mbfb + t * 64 + pb * 16 + hi * 8);

        const u16* ktc = kt[cur];
        const u16* vtc = vt[cur];

        // QK^T swapped: both halves (4 independent chains)
        f32x16 s0, s1;
#pragma unroll
        for (int r = 0; r < 16; r++) { s0[r] = 0.f; s1[r] = 0.f; }
        __builtin_amdgcn_s_setprio(1);
#pragma unroll
        for (int kb = 0; kb < 4; kb++) {
            int slot = ((kb * 2 + hi) ^ c7 ^ c3) << 3;
            s16x8 kf0 = *(const s16x8*)&ktc[c * 64 + slot];
            s16x8 kf1 = *(const s16x8*)&ktc[(32 + c) * 64 + slot];
            s0 = __builtin_amdgcn_mfma_f32_32x32x16_bf16(kf0, qa[kb], s0, 0, 0, 0);
            s1 = __builtin_amdgcn_mfma_f32_32x32x16_bf16(kf1, qa[kb], s1, 0, 0, 0);
        }
        __builtin_amdgcn_s_setprio(0);

        // ---- half 0: exp/pack(s0) -> PV pb 0-1 ----
        {
            float p0a[16];
#pragma unroll
            for (int r = 0; r < 16; r++) p0a[r] = fast_exp2(s0[r]);
            u32 pka[8];
#pragma unroll
            for (int i = 0; i < 8; i++) pka[i] = pkbf(p0a[2 * i], p0a[2 * i + 1]);
            pl32swap(pka[0], pka[2]); pl32swap(pka[1], pka[3]);
            pl32swap(pka[4], pka[6]); pl32swap(pka[5], pka[7]);
            union { u32 u[4]; s16x8 h; } fr[2];
#pragma unroll
            for (int i = 0; i < 4; i++) {
                fr[0].u[i] = pka[i];
                fr[1].u[i] = pka[4 + i];
            }
            __builtin_amdgcn_s_setprio(1);
#pragma unroll
            for (int pb = 0; pb < 2; pb++) {
                int slot = ((pb * 2 + hi) ^ c7 ^ c3) << 3;
                s16x8 vf0 = *(const s16x8*)&vtc[c * 64 + slot];
                s16x8 vf1 = *(const s16x8*)&vtc[(32 + c) * 64 + slot];
                o0 = __builtin_amdgcn_mfma_f32_32x32x16_bf16(vf0, fr[pb].h, o0, 0, 0, 0);
                o1 = __builtin_amdgcn_mfma_f32_32x32x16_bf16(vf1, fr[pb].h, o1, 0, 0, 0);
                lacc = __builtin_amdgcn_mfma_f32_32x32x16_bf16(mf[pb], fr[pb].h, lacc, 0, 0, 0);
            }
            __builtin_amdgcn_s_setprio(0);
        }

        // ---- half 1: exp/pack(s1) -> PV pb 2-3 (overlaps half 0's MFMAs) ----
        {
            float p1a[16];
#pragma unroll
            for (int r = 0; r < 16; r++) p1a[r] = fast_exp2(s1[r]);
            u32 pkb2[8];
#pragma unroll
            for (int i = 0; i < 8; i++) pkb2[i] = pkbf(p1a[2 * i], p1a[2 * i + 1]);
            pl32swap(pkb2[0], pkb2[2]); pl32swap(pkb2[1], pkb2[3]);
            pl32swap(pkb2[4], pkb2[6]); pl32swap(pkb2[5], pkb2[7]);
            union { u32 u[4]; s16x8 h; } fr[2];
#pragma unroll
            for (int i = 0; i < 4; i++) {
                fr[0].u[i] = pkb2[i];
                fr[1].u[i] = pkb2[4 + i];
            }
            __builtin_amdgcn_s_setprio(1);
#pragma unroll
            for (int pb = 0; pb < 2; pb++) {
                int slot = (((pb + 2) * 2 + hi) ^ c7 ^ c3) << 3;
                s16x8 vf0 = *(const s16x8*)&vtc[c * 64 + slot];
                s16x8 vf1 = *(const s16x8*)&vtc[(32 + c) * 64 + slot];
                o0 = __builtin_amdgcn_mfma_f32_32x32x16_bf16(vf0, fr[pb].h, o0, 0, 0, 0);
                o1 = __builtin_amdgcn_mfma_f32_32x32x16_bf16(vf1, fr[pb].h, o1, 0, 0, 0);
                lacc = __builtin_amdgcn_mfma_f32_32x32x16_bf16(mf[pb + 2], fr[pb].h, lacc, 0, 0, 0);
            }
            __builtin_amdgcn_s_setprio(0);
        }
    }

    float linv = 1.f / lacc[0];

    // epilogue: transpose O through LDS (reuse kt), coalesced global write.
    __syncthreads();
    u32* osh = (u32*)kt + w * 1024;
#pragma unroll
    for (int r = 0; r < 16; r += 2) {
        int d = (r & 3) + 8 * (r >> 2) + 4 * hi;
        u32 plo = pkbf(o0[r] * linv, o0[r + 1] * linv);
        u32 phi = pkbf(o1[r] * linv, o1[r + 1] * linv);
        int dc0 = d >> 1, dc1 = (d + 32) >> 1;
        osh[c * 32 + (((dc0 >> 2) ^ c7) << 2) + (dc0 & 3)] = plo;
        osh[c * 32 + (((dc1 >> 2) ^ c7) << 2) + (dc1 & 3)] = phi;
    }
    __syncthreads();
#pragma unroll
    for (int i = 0; i < 4; i++) {
        int row = 8 * i + (lane >> 3);
        int jj = lane & 7;
        u32 v0 = osh[row * 32 + ((jj ^ (row & 7)) << 2) + 0];
        u32 v1 = osh[row * 32 + ((jj ^ (row & 7)) << 2) + 1];
        u32 v2 = osh[row * 32 + ((jj ^ (row & 7)) << 2) + 2];
        u32 v3 = osh[row * 32 + ((jj ^ (row & 7)) << 2) + 3];
        u32* gp = (u32*)(attn + ((size_t)b * NLQ + qw0 + row) * ND + h * NHD + jj * 8);
        gp[0] = v0; gp[1] = v1; gp[2] = v2; gp[3] = v3;
    }
}

extern "C" void kernel_launch(void* const* d_in, const int* in_sizes, int n_in,
                              void* d_out, int out_size, void* d_ws, size_t ws_size,
                              hipStream_t stream) {
    const float* x_q = (const float*)d_in[0];
    const float* x_kv = (const float*)d_in[1];
    const int* mask = (const int*)d_in[2];
    const float* Wq = (const float*)d_in[3];
    const float* bq = (const float*)d_in[4];
    const float* Wk = (const float*)d_in[5];
    const float* bk = (const float*)d_in[6];
    const float* Wv = (const float*)d_in[7];
    const float* bv = (const float*)d_in[8];
    const float* Wo = (const float*)d_in[9];
    const float* bo = (const float*)d_in[10];
    float* out = (float*)d_out;

    size_t off = 0;
    auto carve = [&](size_t bytes) {
        void* p = (char*)d_ws + off;
        off += (bytes + 255) & ~(size_t)255;
        return p;
    };
    u16* xq_bf = (u16*)carve((size_t)NB * NLQ * ND * 2);
    u16* xkv_bf = (u16*)carve((size_t)NB * NLKV * ND * 2);
    u16* wq_t = (u16*)carve((size_t)ND * ND * 2);
    u16* wkv_t = (u16*)carve((size_t)2 * ND * ND * 2);
    u16* wo_t = (u16*)carve((size_t)ND * ND * 2);
    u16* Qh = (u16*)carve((size_t)NB * NH * NLQ * NHD * 2);
    u16* Kh = (u16*)carve((size_t)NB * NH * NLKV * NHD * 2);
    u16* VTh = (u16*)carve((size_t)NB * NH * NLKV * NHD * 2);
    u16* attn_bf = (u16*)carve((size_t)NB * NLQ * ND * 2);
    u16* mbfw = (u16*)carve((size_t)NB * NLKV * 2);

    prep_kernel<<<dim3(10272), 256, 0, stream>>>(
        x_q, x_kv, mask, Wq, Wk, Wv, Wo,
        xq_bf, xkv_bf, mbfw, wq_t, wkv_t, wkv_t + (size_t)ND * ND, wo_t);
    qkv_kernel<<<dim3(1280), 512, 0, stream>>>(xq_bf, xkv_bf, wq_t, wkv_t,
                                               bq, bk, bv, mask, Qh, Kh, VTh);
    attn_kernel<<<dim3(16, 32), 256, 0, stream>>>(Qh, Kh, VTh, mbfw, attn_bf);
    ogemm_kernel<<<dim3(64, 8), 256, 0, stream>>>(attn_bf, wo_t, bo, out);
}

// Round 21
// 196.303 us; speedup vs baseline: 1.1983x; 1.0162x over previous
//
#include <hip/hip_runtime.h>
#include <hip/hip_bf16.h>

typedef unsigned short u16;
typedef unsigned int u32;
typedef __attribute__((ext_vector_type(8))) unsigned short u16x8;
typedef __attribute__((ext_vector_type(8))) short s16x8;
typedef __attribute__((ext_vector_type(4))) float f32x4;
typedef __attribute__((ext_vector_type(16))) float f32x16;

#define NB 2
#define NLQ 2048
#define NLKV 4096
#define ND 1024
#define NH 16
#define NHD 64
#define SCALE 0.125f
#define QSC (SCALE * 1.44269504f)  // fold scale+log2e into Q

// async global->LDS, 16B per lane; dest = uniform base + lane*16
#define GL16(g, l)                                                            \
    __builtin_amdgcn_global_load_lds(                                         \
        (const __attribute__((address_space(1))) void*)(g),                   \
        (__attribute__((address_space(3))) void*)(l), 16, 0, 0)

__device__ __forceinline__ u16 f2bf(float f) {
    __hip_bfloat16 h = __float2bfloat16(f);
    return *(u16*)&h;
}

__device__ __forceinline__ float fast_exp2(float x) {
    float r;
    asm("v_exp_f32 %0, %1" : "=v"(r) : "v"(x));
    return r;
}

__device__ __forceinline__ u32 pkbf(float lo, float hi_) {
    u32 r;
    asm("v_cvt_pk_bf16_f32 %0, %1, %2" : "=v"(r) : "v"(lo), "v"(hi_));
    return r;
}

// vdst.hi32lanes <-> vsrc.lo32lanes
__device__ __forceinline__ void pl32swap(u32& a, u32& b) {
    asm("v_permlane32_swap_b32 %0, %1" : "+v"(a), "+v"(b));
}

// ---------- unified prep: x f32->bf16 | mask->bf16 | 4x weight transpose ----------
__global__ __launch_bounds__(256) void prep_kernel(
    const float* __restrict__ xq, const float* __restrict__ xkv,
    const int* __restrict__ mask,
    const float* __restrict__ w0, const float* __restrict__ w1,
    const float* __restrict__ w2, const float* __restrict__ w3,
    u16* __restrict__ oq, u16* __restrict__ okv, u16* __restrict__ mbf,
    u16* __restrict__ o0, u16* __restrict__ o1,
    u16* __restrict__ o2, u16* __restrict__ o3) {
    __shared__ float t[32][33];
    const int bid = blockIdx.x;
    const int tid = threadIdx.x;
    if (bid < 6144) {
        const float* in;
        u16* out;
        int i0;
        if (bid < 2048) { in = xq; out = oq; i0 = bid; }
        else { in = xkv; out = okv; i0 = bid - 2048; }
        int i = i0 * 256 + tid;
        const float4* p = (const float4*)in;
        float4 a = p[2 * i], b = p[2 * i + 1];
        u16x8 o;
        o[0] = f2bf(a.x); o[1] = f2bf(a.y); o[2] = f2bf(a.z); o[3] = f2bf(a.w);
        o[4] = f2bf(b.x); o[5] = f2bf(b.y); o[6] = f2bf(b.z); o[7] = f2bf(b.w);
        ((u16x8*)out)[i] = o;
        return;
    }
    if (bid < 6176) {
        int g = (bid - 6144) * 256 + tid;
        mbf[g] = mask[g] ? 0x3F80 : 0;  // bf16 1.0
        return;
    }
    int tb = bid - 6176;
    int z = tb >> 10;
    int rem = tb & 1023;
    int n0 = (rem & 31) * 32, k0 = (rem >> 5) * 32;
    const float* w = z == 0 ? w0 : z == 1 ? w1 : z == 2 ? w2 : w3;
    u16* o = z == 0 ? o0 : z == 1 ? o1 : z == 2 ? o2 : o3;
    int tx = tid & 31, ty = tid >> 5;
#pragma unroll
    for (int i = 0; i < 4; i++) t[ty + 8 * i][tx] = w[(k0 + ty + 8 * i) * ND + n0 + tx];
    __syncthreads();
#pragma unroll
    for (int i = 0; i < 4; i++) o[(n0 + ty + 8 * i) * ND + k0 + tx] = f2bf(t[tx][ty + 8 * i]);
}

// ---------- unified QKV projection GEMM v3 (R19-proven): BK=64 + XOR swizzle ----------
__global__ __launch_bounds__(512) void qkv_kernel(
    const u16* __restrict__ xq, const u16* __restrict__ xkv,
    const u16* __restrict__ wq_t, const u16* __restrict__ wkv_t,
    const float* __restrict__ bq, const float* __restrict__ bk,
    const float* __restrict__ bv, const int* __restrict__ vmask,
    u16* __restrict__ Qh, u16* __restrict__ Kh, u16* __restrict__ VTh) {
    const int bid = blockIdx.x;
    const int swz = (bid & 7) * 160 + (bid >> 3);
    const bool isQ = swz < 256;
    int m0, n0;
    const u16 *A, *Bt;
    if (isQ) {
        m0 = (swz >> 3) * 128; n0 = (swz & 7) * 128;
        A = xq; Bt = wq_t;
    } else {
        int t2 = swz - 256;
        m0 = (t2 >> 4) * 128; n0 = (t2 & 15) * 128;
        A = xkv; Bt = wkv_t;
    }
    const bool isV = !isQ && n0 >= 1024;

    __shared__ __align__(16) u16 As[128 * 64];
    __shared__ __align__(16) u16 Bs[128 * 64];
    const int tid = threadIdx.x;
    const int lane = tid & 63, w = tid >> 6;
    const int wr = w >> 2, wc = w & 3;
    const int lr = lane & 15, lg = lane >> 4;
    const int l7 = lr & 7;

    f32x4 acc[4][2];
#pragma unroll
    for (int i = 0; i < 4; i++)
#pragma unroll
        for (int j = 0; j < 2; j++)
#pragma unroll
            for (int r = 0; r < 4; r++) acc[i][j][r] = 0.f;

    const int srow = tid >> 3, sj = tid & 7;
    const int sx8 = (sj ^ (srow & 7)) * 8;
    const u16* Ag1 = A + (size_t)(m0 + srow) * ND + sx8;
    const u16* Ag2 = A + (size_t)(m0 + 64 + srow) * ND + sx8;
    const u16* Bg1 = Bt + (size_t)(n0 + srow) * ND + sx8;
    const u16* Bg2 = Bt + (size_t)(n0 + 64 + srow) * ND + sx8;
    u16* lA1 = &As[w * 512];
    u16* lA2 = &As[4096 + w * 512];
    u16* lB1 = &Bs[w * 512];
    u16* lB2 = &Bs[4096 + w * 512];

    for (int kt = 0; kt < ND; kt += 64) {
        GL16(Ag1 + kt, lA1);
        GL16(Ag2 + kt, lA2);
        GL16(Bg1 + kt, lB1);
        GL16(Bg2 + kt, lB2);
        __syncthreads();

#pragma unroll
        for (int kk = 0; kk < 2; kk++) {
            const int slot = ((kk * 4 + lg) ^ l7) * 8;
            s16x8 af[4], bf[2];
#pragma unroll
            for (int i = 0; i < 4; i++)
                af[i] = *(const s16x8*)&As[(wr * 64 + i * 16 + lr) * 64 + slot];
#pragma unroll
            for (int j = 0; j < 2; j++)
                bf[j] = *(const s16x8*)&Bs[(wc * 32 + j * 16 + lr) * 64 + slot];
            if (isV) {
#pragma unroll
                for (int mi = 0; mi < 4; mi++)
#pragma unroll
                    for (int ni = 0; ni < 2; ni++)
                        acc[mi][ni] = __builtin_amdgcn_mfma_f32_16x16x32_bf16(
                            bf[ni], af[mi], acc[mi][ni], 0, 0, 0);
            } else {
#pragma unroll
                for (int mi = 0; mi < 4; mi++)
#pragma unroll
                    for (int ni = 0; ni < 2; ni++)
                        acc[mi][ni] = __builtin_amdgcn_mfma_f32_16x16x32_bf16(
                            af[mi], bf[ni], acc[mi][ni], 0, 0, 0);
            }
        }
        __syncthreads();
    }

#pragma unroll
    for (int mi = 0; mi < 4; mi++)
#pragma unroll
        for (int ni = 0; ni < 2; ni++)
#pragma unroll
            for (int r = 0; r < 4; r++) {
                if (isQ) {
                    int m = m0 + wr * 64 + mi * 16 + lg * 4 + r;
                    int n = n0 + wc * 32 + ni * 16 + lr;
                    int h = n >> 6, d = n & 63;
                    int b = m >> 11, lq = m & 2047;
                    Qh[((((size_t)b * NH + h) * NLQ + lq) << 6) + d] =
                        f2bf((acc[mi][ni][r] + bq[n]) * QSC);
                } else if (!isV) {
                    int m = m0 + wr * 64 + mi * 16 + lg * 4 + r;
                    int n = n0 + wc * 32 + ni * 16 + lr;
                    int h = n >> 6, d = n & 63;
                    int b = m >> 12, lkv = m & 4095;
                    Kh[((((size_t)b * NH + h) * NLKV + lkv) << 6) + d] =
                        f2bf(acc[mi][ni][r] + bk[n]);
                } else {
                    int n2 = (n0 - 1024) + wc * 32 + ni * 16 + lg * 4 + r;
                    int m = m0 + wr * 64 + mi * 16 + lr;
                    int h = n2 >> 6, d = n2 & 63;
                    int b = m >> 12, lkv = m & 4095;
                    float val = vmask[(size_t)b * NLKV + lkv]
                                    ? acc[mi][ni][r] + bv[n2] : 0.f;
                    VTh[(((size_t)b * NH + h) * NHD + d) * NLKV + lkv] = f2bf(val);
                }
            }
}

// ---------- O-projection GEMM v2 (R20-proven): 64x128 tile, BK=64 + XOR swizzle ----------
__global__ __launch_bounds__(256) void ogemm_kernel(
    const u16* __restrict__ A, const u16* __restrict__ Bt,
    const float* __restrict__ bias, float* __restrict__ Cout) {
    __shared__ __align__(16) u16 As[64 * 64];
    __shared__ __align__(16) u16 Bs[128 * 64];
    const int m0 = blockIdx.x * 64;
    const int n0 = blockIdx.y * 128;
    const int tid = threadIdx.x;
    const int lane = tid & 63, w = tid >> 6;
    const int wr = w >> 1, wc = w & 1;  // 2x2 wave grid
    const int lr = lane & 15, lg = lane >> 4;
    const int l7 = lr & 7;

    f32x4 acc[2][4];
#pragma unroll
    for (int i = 0; i < 2; i++)
#pragma unroll
        for (int j = 0; j < 4; j++)
#pragma unroll
            for (int r = 0; r < 4; r++) acc[i][j][r] = 0.f;

    const int srow = tid >> 3, sj = tid & 7;
    const int sx8 = (sj ^ (srow & 7)) * 8;
    const u16* Ag1 = A + (size_t)(m0 + srow) * ND + sx8;
    const u16* Ag2 = A + (size_t)(m0 + 32 + srow) * ND + sx8;
    const u16* Bg1 = Bt + (size_t)(n0 + srow) * ND + sx8;
    const u16* Bg2 = Bt + (size_t)(n0 + 32 + srow) * ND + sx8;
    const u16* Bg3 = Bt + (size_t)(n0 + 64 + srow) * ND + sx8;
    const u16* Bg4 = Bt + (size_t)(n0 + 96 + srow) * ND + sx8;
    u16* lA1 = &As[w * 512];
    u16* lA2 = &As[2048 + w * 512];
    u16* lB1 = &Bs[w * 512];
    u16* lB2 = &Bs[2048 + w * 512];
    u16* lB3 = &Bs[4096 + w * 512];
    u16* lB4 = &Bs[6144 + w * 512];

    for (int kt = 0; kt < ND; kt += 64) {
        GL16(Ag1 + kt, lA1);
        GL16(Ag2 + kt, lA2);
        GL16(Bg1 + kt, lB1);
        GL16(Bg2 + kt, lB2);
        GL16(Bg3 + kt, lB3);
        GL16(Bg4 + kt, lB4);
        __syncthreads();

#pragma unroll
        for (int kk = 0; kk < 2; kk++) {
            const int slot = ((kk * 4 + lg) ^ l7) * 8;
            s16x8 af[2], bf[4];
#pragma unroll
            for (int i = 0; i < 2; i++)
                af[i] = *(const s16x8*)&As[(wr * 32 + i * 16 + lr) * 64 + slot];
#pragma unroll
            for (int j = 0; j < 4; j++)
                bf[j] = *(const s16x8*)&Bs[(wc * 64 + j * 16 + lr) * 64 + slot];
#pragma unroll
            for (int mi = 0; mi < 2; mi++)
#pragma unroll
                for (int ni = 0; ni < 4; ni++)
                    acc[mi][ni] = __builtin_amdgcn_mfma_f32_16x16x32_bf16(
                        af[mi], bf[ni], acc[mi][ni], 0, 0, 0);
        }
        __syncthreads();
    }

#pragma unroll
    for (int mi = 0; mi < 2; mi++)
#pragma unroll
        for (int ni = 0; ni < 4; ni++)
#pragma unroll
            for (int r = 0; r < 4; r++) {
                int m = m0 + wr * 32 + mi * 16 + lg * 4 + r;
                int n = n0 + wc * 64 + ni * 16 + lr;
                Cout[(size_t)m * ND + n] = acc[mi][ni][r] + bias[n];
            }
}

// ---------- flash attention (R16/R18-proven body, reorder reverted) ----------
// swapped QK^T + in-register P (cvt_pk+permlane) + l via mask-MFMA + T5 setprio;
// XCD bh-locality remap (FETCH 135->20.5MB) + full-rank XOR swizzle (conflicts
// 8.5M->197K). Monolithic exp->pack->PV ordering (R20's per-half split regressed).
__global__ __launch_bounds__(256) void attn_kernel(
    const u16* __restrict__ Qh, const u16* __restrict__ Kh,
    const u16* __restrict__ VTh, const u16* __restrict__ mbf,
    u16* __restrict__ attn) {
    const int l = blockIdx.x + 16 * blockIdx.y;
    const int qt = l >> 5;
    const int bh = (l & 7) * 4 + ((l >> 3) & 3);
    const int b = bh >> 4, h = bh & 15;
    const int tid = threadIdx.x;
    const int lane = tid & 63, w = tid >> 6;
    const int c = lane & 31, hi = lane >> 5;
    const int c7 = c & 7, c3 = (c >> 3) & 3;

    __shared__ __align__(16) u16 kt[2][4096];
    __shared__ __align__(16) u16 vt[2][4096];

    const int qw0 = qt * 128 + w * 32;
    const u16* Qb = Qh + (size_t)bh * NLQ * NHD;
    const u16* Kb = Kh + (size_t)bh * NLKV * NHD;
    const u16* VTb = VTh + (size_t)bh * NHD * NLKV;
    const u16* mbfb = mbf + (size_t)b * NLKV;

    // Q B-fragments: lane holds Q[qw0+c][kb*16 + hi*8 .. +7]
    s16x8 qa[4];
#pragma unroll
    for (int kb = 0; kb < 4; kb++)
        qa[kb] = *(const s16x8*)(Qb + (size_t)(qw0 + c) * NHD + kb * 16 + hi * 8);

    f32x16 o0, o1, lacc;
#pragma unroll
    for (int r = 0; r < 16; r++) { o0[r] = 0.f; o1[r] = 0.f; lacc[r] = 0.f; }

    // staging: row srow & srow+32, chunk sj; slot j holds logical chunk
    // j ^ (row&7) ^ ((row>>3)&3)   (key(row+32) == key(row))
    const int srow = 8 * w + (lane >> 3);
    const int sj = lane & 7;
    const int sx8 = (sj ^ (srow & 7) ^ ((srow >> 3) & 3)) * 8;
    const u16* kS1 = Kb + (size_t)srow * NHD + sx8;
    const u16* kS2 = Kb + (size_t)(srow + 32) * NHD + sx8;
    const u16* vS1 = VTb + (size_t)srow * NLKV + sx8;
    const u16* vS2 = VTb + (size_t)(srow + 32) * NLKV + sx8;
    const int d1 = w * 512, d2 = 2048 + w * 512;

    // prologue: stage tile 0 into buffer 0
    GL16(kS1, &kt[0][d1]);
    GL16(kS2, &kt[0][d2]);
    GL16(vS1, &vt[0][d1]);
    GL16(vS2, &vt[0][d2]);

    const int NT = NLKV / 64;
    for (int t = 0; t < NT; t++) {
        const int cur = t & 1;
        __syncthreads();  // buf[cur] staged (vmcnt drained) + buf[cur^1] free
        if (t + 1 < NT) {
            size_t kvo = (size_t)(t + 1) * 64;
            GL16(kS1 + kvo * NHD, &kt[cur ^ 1][d1]);
            GL16(kS2 + kvo * NHD, &kt[cur ^ 1][d2]);
            GL16(vS1 + kvo, &vt[cur ^ 1][d1]);
            GL16(vS2 + kvo, &vt[cur ^ 1][d2]);
        }
        // mask A-fragments (broadcast rows)
        s16x8 mf[4];
#pragma unroll
        for (int pb = 0; pb < 4; pb++)
            mf[pb] = *(const s16x8*)(mbfb + t * 64 + pb * 16 + hi * 8);

        const u16* ktc = kt[cur];
        const u16* vtc = vt[cur];

        // QK^T swapped: s0 = S^T rows kv 0..31, s1 = rows 32..63; col q = c
        f32x16 s0, s1;
#pragma unroll
        for (int r = 0; r < 16; r++) { s0[r] = 0.f; s1[r] = 0.f; }
        __builtin_amdgcn_s_setprio(1);
#pragma unroll
        for (int kb = 0; kb < 4; kb++) {
            int slot = ((kb * 2 + hi) ^ c7 ^ c3) << 3;
            s16x8 kf0 = *(const s16x8*)&ktc[c * 64 + slot];
            s16x8 kf1 = *(const s16x8*)&ktc[(32 + c) * 64 + slot];
            s0 = __builtin_amdgcn_mfma_f32_32x32x16_bf16(kf0, qa[kb], s0, 0, 0, 0);
            s1 = __builtin_amdgcn_mfma_f32_32x32x16_bf16(kf1, qa[kb], s1, 0, 0, 0);
        }
        __builtin_amdgcn_s_setprio(0);

        // softmax: pure exp2 (Q pre-scaled; mask via V-zeroing + l-MFMA)
        float p0a[16], p1a[16];
#pragma unroll
        for (int r = 0; r < 16; r++) {
            p0a[r] = fast_exp2(s0[r]);
            p1a[r] = fast_exp2(s1[r]);
        }

        // pack to bf16 pairs + permlane swap -> PV B-fragments
        u32 pka[8], pkb2[8];
#pragma unroll
        for (int i = 0; i < 8; i++) {
            pka[i] = pkbf(p0a[2 * i], p0a[2 * i + 1]);
            pkb2[i] = pkbf(p1a[2 * i], p1a[2 * i + 1]);
        }
        pl32swap(pka[0], pka[2]); pl32swap(pka[1], pka[3]);
        pl32swap(pka[4], pka[6]); pl32swap(pka[5], pka[7]);
        pl32swap(pkb2[0], pkb2[2]); pl32swap(pkb2[1], pkb2[3]);
        pl32swap(pkb2[4], pkb2[6]); pl32swap(pkb2[5], pkb2[7]);

        union { u32 u[4]; s16x8 h; } fr[4];
#pragma unroll
        for (int i = 0; i < 4; i++) {
            fr[0].u[i] = pka[i];
            fr[1].u[i] = pka[4 + i];
            fr[2].u[i] = pkb2[i];
            fr[3].u[i] = pkb2[4 + i];
        }

        // PV: O^T[d][q=c] += V^T[d][kv] * P ; l via mask-MFMA on same P frags
        __builtin_amdgcn_s_setprio(1);
#pragma unroll
        for (int pb = 0; pb < 4; pb++) {
            int slot = ((pb * 2 + hi) ^ c7 ^ c3) << 3;
            s16x8 vf0 = *(const s16x8*)&vtc[c * 64 + slot];
            s16x8 vf1 = *(const s16x8*)&vtc[(32 + c) * 64 + slot];
            o0 = __builtin_amdgcn_mfma_f32_32x32x16_bf16(vf0, fr[pb].h, o0, 0, 0, 0);
            o1 = __builtin_amdgcn_mfma_f32_32x32x16_bf16(vf1, fr[pb].h, o1, 0, 0, 0);
            lacc = __builtin_amdgcn_mfma_f32_32x32x16_bf16(mf[pb], fr[pb].h, lacc, 0, 0, 0);
        }
        __builtin_amdgcn_s_setprio(0);
    }

    // lacc rows are all identical = l[q=c] over the full kv range
    float linv = 1.f / lacc[0];

    // epilogue: transpose O through LDS (reuse kt), coalesced global write.
    __syncthreads();
    u32* osh = (u32*)kt + w * 1024;  // per-wave [32 rows][32 dwords]
#pragma unroll
    for (int r = 0; r < 16; r += 2) {
        int d = (r & 3) + 8 * (r >> 2) + 4 * hi;
        u32 plo = pkbf(o0[r] * linv, o0[r + 1] * linv);
        u32 phi = pkbf(o1[r] * linv, o1[r + 1] * linv);
        int dc0 = d >> 1, dc1 = (d + 32) >> 1;
        osh[c * 32 + (((dc0 >> 2) ^ c7) << 2) + (dc0 & 3)] = plo;
        osh[c * 32 + (((dc1 >> 2) ^ c7) << 2) + (dc1 & 3)] = phi;
    }
    __syncthreads();
#pragma unroll
    for (int i = 0; i < 4; i++) {
        int row = 8 * i + (lane >> 3);
        int jj = lane & 7;
        u32 v0 = osh[row * 32 + ((jj ^ (row & 7)) << 2) + 0];
        u32 v1 = osh[row * 32 + ((jj ^ (row & 7)) << 2) + 1];
        u32 v2 = osh[row * 32 + ((jj ^ (row & 7)) << 2) + 2];
        u32 v3 = osh[row * 32 + ((jj ^ (row & 7)) << 2) + 3];
        u32* gp = (u32*)(attn + ((size_t)b * NLQ + qw0 + row) * ND + h * NHD + jj * 8);
        gp[0] = v0; gp[1] = v1; gp[2] = v2; gp[3] = v3;
    }
}

extern "C" void kernel_launch(void* const* d_in, const int* in_sizes, int n_in,
                              void* d_out, int out_size, void* d_ws, size_t ws_size,
                              hipStream_t stream) {
    const float* x_q = (const float*)d_in[0];
    const float* x_kv = (const float*)d_in[1];
    const int* mask = (const int*)d_in[2];
    const float* Wq = (const float*)d_in[3];
    const float* bq = (const float*)d_in[4];
    const float* Wk = (const float*)d_in[5];
    const float* bk = (const float*)d_in[6];
    const float* Wv = (const float*)d_in[7];
    const float* bv = (const float*)d_in[8];
    const float* Wo = (const float*)d_in[9];
    const float* bo = (const float*)d_in[10];
    float* out = (float*)d_out;

    size_t off = 0;
    auto carve = [&](size_t bytes) {
        void* p = (char*)d_ws + off;
        off += (bytes + 255) & ~(size_t)255;
        return p;
    };
    u16* xq_bf = (u16*)carve((size_t)NB * NLQ * ND * 2);
    u16* xkv_bf = (u16*)carve((size_t)NB * NLKV * ND * 2);
    u16* wq_t = (u16*)carve((size_t)ND * ND * 2);
    u16* wkv_t = (u16*)carve((size_t)2 * ND * ND * 2);
    u16* wo_t = (u16*)carve((size_t)ND * ND * 2);
    u16* Qh = (u16*)carve((size_t)NB * NH * NLQ * NHD * 2);
    u16* Kh = (u16*)carve((size_t)NB * NH * NLKV * NHD * 2);
    u16* VTh = (u16*)carve((size_t)NB * NH * NLKV * NHD * 2);
    u16* attn_bf = (u16*)carve((size_t)NB * NLQ * ND * 2);
    u16* mbfw = (u16*)carve((size_t)NB * NLKV * 2);

    prep_kernel<<<dim3(10272), 256, 0, stream>>>(
        x_q, x_kv, mask, Wq, Wk, Wv, Wo,
        xq_bf, xkv_bf, mbfw, wq_t, wkv_t, wkv_t + (size_t)ND * ND, wo_t);
    qkv_kernel<<<dim3(1280), 512, 0, stream>>>(xq_bf, xkv_bf, wq_t, wkv_t,
                                               bq, bk, bv, mask, Qh, Kh, VTh);
    attn_kernel<<<dim3(16, 32), 256, 0, stream>>>(Qh, Kh, VTh, mbfw, attn_bf);
    ogemm_kernel<<<dim3(64, 8), 256, 0, stream>>>(attn_bf, wo_t, bo, out);
}